// Round 15
// baseline (363.768 us; speedup 1.0000x reference)
//
#include <hip/hip_runtime.h>
#include <math.h>
#include <float.h>

#define L_   4096
#define M_   8192
#define H_   8
#define D_   64
#define KK   45          // 5 * ceil(ln(4096))

// ws layout in float2 units
#define WS_C   0         // c[4096]  : e^{-i pi j^2 / 8191}
#define WS_D   4096      // d[4096]  : e^{+i pi j^2 / 8190}
#define WS_TW  8192      // tw[8192] : e^{-2 pi i j / 8192} (fp64-accurate; setup_filters only)
#define WS_H1  16384     // H1s[8192]: radix4-DIF(conj-chirp c), pre-scaled 1/8192, digit-reversed
#define WS_H2  24576     // H2s[8192]: same for d
#define WS_SK  32768     // Kspec[256][4096] float2 (8 MB)
#define WS_SQ  1081344   // Qspec[256][4096] float2 (8 MB)   = 32768 + 256*4096
// total ws: ~16.25 MB

__device__ __forceinline__ float2 cadd(float2 a, float2 b) { return make_float2(a.x + b.x, a.y + b.y); }
__device__ __forceinline__ float2 csub(float2 a, float2 b) { return make_float2(a.x - b.x, a.y - b.y); }
__device__ __forceinline__ float2 cmulf(float2 a, float2 b) {
  return make_float2(a.x * b.x - a.y * b.y, a.x * b.y + a.y * b.x);
}
__device__ __forceinline__ float2 cmulcf(float2 a, float2 b) {  // a * conj(b)
  return make_float2(a.x * b.x + a.y * b.y, a.y * b.x - a.x * b.y);
}

// register twiddle: e^{-2 pi i e / 8192}, e in [0, 2048)
__device__ __forceinline__ float2 twf(int e) {
  float s, c;
  __sincosf((float)e * -7.66990394e-4f, &s, &c);   // -2*pi/8192
  return make_float2(c, s);
}

#define R4DIF(BUF) { \
  const float2 a = BUF[i0], b = BUF[i0 + q], c = BUF[i0 + 2 * q], d = BUF[i0 + 3 * q]; \
  const float2 t0 = cadd(a, c), t1 = csub(a, c), t2 = cadd(b, d), t3 = csub(b, d); \
  BUF[i0]         = cadd(t0, t2); \
  BUF[i0 + q]     = cmulf(make_float2(t1.x + t3.y, t1.y - t3.x), w1); \
  BUF[i0 + 2 * q] = cmulf(csub(t0, t2), w2); \
  BUF[i0 + 3 * q] = cmulf(make_float2(t1.x - t3.y, t1.y + t3.x), w3); }

#define R4DIT(BUF) { \
  const float2 z0 = BUF[i0]; \
  const float2 z1 = cmulcf(BUF[i0 + q],     w1); \
  const float2 z2 = cmulcf(BUF[i0 + 2 * q], w2); \
  const float2 z3 = cmulcf(BUF[i0 + 3 * q], w3); \
  const float2 t0 = cadd(z0, z2), t1 = csub(z0, z2), t2 = cadd(z1, z3), u = csub(z1, z3); \
  BUF[i0]         = cadd(t0, t2); \
  BUF[i0 + q]     = make_float2(t1.x - u.y, t1.y + u.x); \
  BUF[i0 + 2 * q] = csub(t0, t2); \
  BUF[i0 + 3 * q] = make_float2(t1.x + u.y, t1.y - u.x); }

// register-array radix-4 butterflies (all indices compile-time at call sites)
__device__ __forceinline__ void bfly4_dif(float2 x[4], float2 w1, float2 w2, float2 w3) {
  const float2 t0 = cadd(x[0], x[2]), t1 = csub(x[0], x[2]);
  const float2 t2 = cadd(x[1], x[3]), t3 = csub(x[1], x[3]);
  x[0] = cadd(t0, t2);
  x[1] = cmulf(make_float2(t1.x + t3.y, t1.y - t3.x), w1);
  x[2] = cmulf(csub(t0, t2), w2);
  x[3] = cmulf(make_float2(t1.x - t3.y, t1.y + t3.x), w3);
}
__device__ __forceinline__ void bfly4_dit(float2 x[4], float2 w1, float2 w2, float2 w3) {
  const float2 z0 = x[0];
  const float2 z1 = cmulcf(x[1], w1);
  const float2 z2 = cmulcf(x[2], w2);
  const float2 z3 = cmulcf(x[3], w3);
  const float2 t0 = cadd(z0, z2), t1 = csub(z0, z2), t2 = cadd(z1, z3), u = csub(z1, z3);
  x[0] = cadd(t0, t2);
  x[1] = make_float2(t1.x - u.y, t1.y + u.x);
  x[2] = csub(t0, t2);
  x[3] = make_float2(t1.x + u.y, t1.y - u.x);
}

// fused r2 + H-pointwise + r2inv on one float2-pair packed in a float4
__device__ __forceinline__ float4 midpair(float4 a, float4 h) {
  float2 u = make_float2(a.x + a.z, a.y + a.w);
  float2 v = make_float2(a.x - a.z, a.y - a.w);
  u = cmulf(u, make_float2(h.x, h.y));
  v = cmulf(v, make_float2(h.z, h.w));
  return make_float4(u.x + v.x, u.y + v.y, u.x - v.x, u.y - v.y);
}

// middle forward stages s=1..5 (1024 threads); sync at each stage start
static __device__ void fwd_stages1(float2* A) {
  const int tid = threadIdx.x;
  #pragma unroll
  for (int s = 1; s < 6; ++s) {
    const int q = 2048 >> (2 * s);
    __syncthreads();
    #pragma unroll
    for (int r = 0; r < 2; ++r) {
      const int bid = tid + (r << 10);
      const int j   = bid & (q - 1);
      const int i0  = ((bid >> (11 - 2 * s)) << (13 - 2 * s)) + j;
      const float2 w1 = twf(j << (2 * s));
      const float2 w2 = cmulf(w1, w1);
      const float2 w3 = cmulf(w2, w1);
      R4DIF(A)
    }
  }
}
static __device__ void inv_stages1(float2* A) {   // s=5..1
  const int tid = threadIdx.x;
  #pragma unroll
  for (int s = 5; s >= 1; --s) {
    const int q = 2048 >> (2 * s);
    __syncthreads();
    #pragma unroll
    for (int r = 0; r < 2; ++r) {
      const int bid = tid + (r << 10);
      const int j   = bid & (q - 1);
      const int i0  = ((bid >> (11 - 2 * s)) << (13 - 2 * s)) + j;
      const float2 w1 = twf(j << (2 * s));
      const float2 w2 = cmulf(w1, w1);
      const float2 w3 = cmulf(w2, w1);
      R4DIT(A)
    }
  }
}

// ---------------- setup: tables (fp64) + Bluestein filters ----------------
template <int NT>
static __device__ void fft_dif_tab(float2* buf, const float2* __restrict__ tw) {
  const int tid = threadIdx.x;
  for (int s = 0; s < 6; ++s) {
    const int q = 2048 >> (2 * s);
    __syncthreads();
    for (int r = 0; r < 2048 / NT; ++r) {
      const int bid = tid + r * NT;
      const int j   = bid & (q - 1);
      const int i0  = ((bid >> (11 - 2 * s)) << (13 - 2 * s)) + j;
      const int e   = j << (2 * s);
      const float2 w1 = tw[e], w2 = tw[2 * e], w3 = tw[3 * e];
      R4DIF(buf)
    }
  }
  __syncthreads();
  for (int r = 0; r < 4096 / NT; ++r) {
    const int i0 = (tid + r * NT) << 1;
    const float2 a = buf[i0], b = buf[i0 + 1];
    buf[i0] = cadd(a, b); buf[i0 + 1] = csub(a, b);
  }
  __syncthreads();
}

extern "C" __global__ void setup_tables(float2* ws) {
  const int idx = blockIdx.x * 512 + threadIdx.x;
  if (idx < 4096) {
    const long p = ((long)idx * idx) % 16382;      // j^2 mod 2*8191
    const double th = -M_PI * (double)p / 8191.0;
    double s, c; sincos(th, &s, &c);
    ws[WS_C + idx] = make_float2((float)c, (float)s);
  } else if (idx < 8192) {
    const int j = idx - 4096;
    const long p = ((long)j * j) % 16380;          // j^2 mod 2*8190
    const double th = M_PI * (double)p / 8190.0;
    double s, c; sincos(th, &s, &c);
    ws[WS_D + j] = make_float2((float)c, (float)s);
  } else if (idx < 16384) {
    const int j = idx - 8192;
    const double th = -M_PI * (double)j / 4096.0;  // e^{-2pi i j/8192}
    double s, c; sincos(th, &s, &c);
    ws[WS_TW + j] = make_float2((float)c, (float)s);
  }
}

extern "C" __global__ __launch_bounds__(512, 1) void setup_filters(float2* ws) {
  __shared__ __align__(16) float2 buf[M_];
  const float2* src = ws + (blockIdx.x == 0 ? WS_C : WS_D);
  float2*       dst = ws + (blockIdx.x == 0 ? WS_H1 : WS_H2);
  const float2* tw  = ws + WS_TW;
  for (int i = threadIdx.x; i < M_; i += 512) {
    float2 val = make_float2(0.f, 0.f);
    if (i != 4096) {                       // kernel support |j| <= 4095
      const int jj = (i <= 4095) ? i : (M_ - i);   // chirp is even in j
      const float2 e = src[jj];
      val = make_float2(e.x, -e.y);        // conj(chirp)
    }
    buf[i] = val;
  }
  fft_dif_tab<512>(buf, tw);
  const float sc = 1.0f / 8192.0f;         // fold IFFT scaling into the filter
  for (int i = threadIdx.x; i < M_; i += 512)
    dst[i] = make_float2(buf[i].x * sc, buf[i].y * sc);
}

// ---------------- inline row projection: stream 1 row (1 MB), 4-lane reduce ----------------
// thread: qt = tid&3 (owns floats [qt*16,qt*16+16) of each row), lgrp = tid>>2 (row in sweep).
#define ROW_ISSUE(BUF, SW) { \
  const size_t f0 = ((size_t)((SW) * 256 + lgrp)) * 128 + qt * 4; \
  BUF[0] = s4[f0]; BUF[1] = s4[f0 + 1]; BUF[2] = s4[f0 + 2]; BUF[3] = s4[f0 + 3]; }

#define ROW_REDUCE(DST, BUF, SW) { \
  float f_ = BUF[0].x * w0.x + BUF[0].y * w0.y + BUF[0].z * w0.z + BUF[0].w * w0.w \
           + BUF[1].x * w1.x + BUF[1].y * w1.y + BUF[1].z * w1.z + BUF[1].w * w1.w \
           + BUF[2].x * w2.x + BUF[2].y * w2.y + BUF[2].z * w2.z + BUF[2].w * w2.w \
           + BUF[3].x * w3.x + BUF[3].y * w3.y + BUF[3].z * w3.z + BUF[3].w * w3.w; \
  f_ += __shfl_xor(f_, 1); f_ += __shfl_xor(f_, 2); \
  if (qt == 0) DST[(SW) * 256 + lgrp] = f_ + bias; }

// CORRECT double-buffer (r14 bugfix): REDUCE(buf, sw) BEFORE ISSUE(buf, sw+2).
// Steady state keeps 2 loads in flight; reduce never reads a clobbered buffer.
#define ROW_STREAM(DST) { \
  float4 pA[4], pB[4]; \
  ROW_ISSUE(pA, 0) \
  ROW_ISSUE(pB, 1) \
  _Pragma("unroll") \
  for (int sw = 0; sw < 16; sw += 2) { \
    ROW_REDUCE(DST, pA, sw) \
    if (sw + 2 < 16) { ROW_ISSUE(pA, sw + 2) } \
    ROW_REDUCE(DST, pB, sw + 1) \
    if (sw + 3 < 16) { ROW_ISSUE(pB, sw + 3) } \
  } }

// ---------------- kernel A: inline proj + forward CZT, one conv per block ----------------
// grid 512: block i handles bh = i&255, which = i>>8 (0=K from keys, 1=Q from queries).
// LDS = 64 KB only -> 2 blocks/CU (32 waves/CU); launch_bounds caps VGPR at 64.
extern "C" __global__ __launch_bounds__(1024, 8)
void autocorr_fwd(const float* __restrict__ queries, const float* __restrict__ keys,
                  const float* __restrict__ Wq, const float* __restrict__ bq,
                  const float* __restrict__ Wk, const float* __restrict__ bk,
                  float2* __restrict__ ws)
{
  __shared__ __align__(16) float2 buf[M_];
  float* rst = reinterpret_cast<float*>(buf) + 8192;   // row staging overlays buf pad half

  const int tid   = threadIdx.x;
  const int bh    = blockIdx.x & 255;
  const int which = blockIdx.x >> 8;     // 0 = K, 1 = Q
  const int b = bh >> 3, h = bh & 7;
  const int qt = tid & 3, lgrp = tid >> 2;

  const float2* c_t = ws + WS_C;
  const float2* H1  = ws + WS_H1;
  const float* src  = (which ? queries : keys) + ((size_t)b * (L_ * H_) + h) * (size_t)D_;
  const float4* s4  = reinterpret_cast<const float4*>(src);
  const float4* W4  = reinterpret_cast<const float4*>(which ? Wq : Wk);
  const float4 w0 = W4[qt * 4 + 0], w1 = W4[qt * 4 + 1];
  const float4 w2 = W4[qt * 4 + 2], w3 = W4[qt * 4 + 3];
  const float bias = which ? bq[0] : bk[0];

  ROW_STREAM(rst)
  __syncthreads();

  // entry fusion: read staged row to regs (staging overlays buf pad), then chirp + fwd s0
  float r0[2], r1[2];
  #pragma unroll
  for (int r = 0; r < 2; ++r) {
    const int bid = tid + (r << 10);
    r0[r] = rst[bid];
    r1[r] = rst[bid + 2048];
  }
  __syncthreads();
  #pragma unroll
  for (int r = 0; r < 2; ++r) {
    const int bid = tid + (r << 10);
    const float2 tw1 = twf(bid);
    const float2 tw2 = cmulf(tw1, tw1);
    const float2 tw3 = cmulf(tw2, tw1);
    const float2 cc0 = c_t[bid], cc1 = c_t[bid + 2048];
    float2 x[4] = { make_float2(r0[r] * cc0.x, r0[r] * cc0.y),
                    make_float2(r1[r] * cc1.x, r1[r] * cc1.y),
                    make_float2(0.f, 0.f), make_float2(0.f, 0.f) };
    bfly4_dif(x, tw1, tw2, tw3);
    #pragma unroll
    for (int k = 0; k < 4; ++k) buf[bid + k * 2048] = x[k];
  }

  fwd_stages1(buf);
  __syncthreads();
  #pragma unroll
  for (int r = 0; r < 4; ++r) {
    const int p = tid + (r << 10);
    const float4 hh = reinterpret_cast<const float4*>(H1)[p];
    reinterpret_cast<float4*>(buf)[p] = midpair(reinterpret_cast<float4*>(buf)[p], hh);
  }
  inv_stages1(buf);
  __syncthreads();

  // exit fusion: inv s0 in regs + chirp-mult + spec store (m < 4096 only)
  float2* spec = ws + (which ? WS_SQ : WS_SK) + (size_t)bh * 4096;
  #pragma unroll
  for (int r = 0; r < 2; ++r) {
    const int bid = tid + (r << 10);
    const float2 tw1 = twf(bid);
    const float2 tw2 = cmulf(tw1, tw1);
    const float2 tw3 = cmulf(tw2, tw1);
    float2 x[4];
    #pragma unroll
    for (int k = 0; k < 4; ++k) x[k] = buf[bid + k * 2048];
    bfly4_dit(x, tw1, tw2, tw3);
    #pragma unroll
    for (int k = 0; k < 2; ++k) {
      const int m = bid + k * 2048;
      spec[m] = cmulf(c_t[m], x[k]);
    }
  }
}

// ---------------- kernel B: inline v-proj + inverse CZT + topk + softmax + gather -------
extern "C" __global__ __launch_bounds__(1024, 1)
void autocorr_inv(const float* __restrict__ values,
                  const float* __restrict__ Wv, const float* __restrict__ bv,
                  const float2* __restrict__ ws, float* __restrict__ outp)
{
  __shared__ __align__(16) float2 buf[M_];   // 64 KB
  __shared__ float  v_lds[L_];               // 16 KB
  __shared__ float  cand_v[16 * KK];
  __shared__ int    cand_i[16 * KK];
  __shared__ float  w_sh[KK];
  __shared__ int    i_sh[KK];

  const int tid = threadIdx.x;
  const int bh  = blockIdx.x;
  const int b = bh >> 3, h = bh & 7;
  const int qt = tid & 3, lgrp = tid >> 2;

  const float2* d_t = ws + WS_D;
  const float2* H2  = ws + WS_H2;
  const float2* SK  = ws + WS_SK + (size_t)bh * 4096;
  const float2* SQ  = ws + WS_SQ + (size_t)bh * 4096;

  // v projection into v_lds (fixed double-buffer stream)
  {
    const float* src = values + ((size_t)b * (L_ * H_) + h) * (size_t)D_;
    const float4* s4 = reinterpret_cast<const float4*>(src);
    const float4* W4 = reinterpret_cast<const float4*>(Wv);
    const float4 w0 = W4[qt * 4 + 0], w1 = W4[qt * 4 + 1];
    const float4 w2 = W4[qt * 4 + 2], w3 = W4[qt * 4 + 3];
    const float bias = bv[0];
    ROW_STREAM(v_lds)
  }

  // entry fusion: F = Q*conj(K), g, g.d, fwd s0 (registers) -> buf
  #pragma unroll
  for (int r = 0; r < 2; ++r) {
    const int bid = tid + (r << 10);
    const float2 tw1 = twf(bid);
    const float2 tw2 = cmulf(tw1, tw1);
    const float2 tw3 = cmulf(tw2, tw1);
    float2 gd[2];
    #pragma unroll
    for (int k = 0; k < 2; ++k) {
      const int m = bid + k * 2048;
      const float2 K = SK[m];
      const float2 Q = SQ[m];
      const float2 F = cmulcf(Q, K);
      float2 g;
      if (m == 0 || m == 4095) g = make_float2(F.x, 0.f);   // DC/Nyquist: Im dropped
      else                     g = make_float2(2.f * F.x, 2.f * F.y);
      gd[k] = cmulf(g, d_t[m]);
    }
    float2 x[4] = { gd[0], gd[1], make_float2(0.f, 0.f), make_float2(0.f, 0.f) };
    bfly4_dif(x, tw1, tw2, tw3);
    #pragma unroll
    for (int k = 0; k < 4; ++k) buf[bid + k * 2048] = x[k];
  }

  fwd_stages1(buf);
  __syncthreads();
  #pragma unroll
  for (int r = 0; r < 4; ++r) {
    const int p = tid + (r << 10);
    const float4 hh = reinterpret_cast<const float4*>(H2)[p];
    reinterpret_cast<float4*>(buf)[p] = midpair(reinterpret_cast<float4*>(buf)[p], hh);
  }
  inv_stages1(buf);
  __syncthreads();

  // exit fusion: inv s0 + score (registers)
  const float SCALE = (float)(1.0 / (8190.0 * 4096.0));   // /8190 (irfft) then /4096 (L)
  float svv[4]; int sii[4];
  #pragma unroll
  for (int r = 0; r < 2; ++r) {
    const int bid = tid + (r << 10);
    const float2 tw1 = twf(bid);
    const float2 tw2 = cmulf(tw1, tw1);
    const float2 tw3 = cmulf(tw2, tw1);
    float2 x[4];
    #pragma unroll
    for (int k = 0; k < 4; ++k) x[k] = buf[bid + k * 2048];
    bfly4_dit(x, tw1, tw2, tw3);
    #pragma unroll
    for (int k = 0; k < 2; ++k) {
      const int t = bid + k * 2048;
      const float2 Z = cmulf(d_t[t], x[k]);
      svv[2 * r + k] = Z.x * SCALE;
      sii[2 * r + k] = t;
    }
  }

  // per-wave top-45
  const int lane = tid & 63, wv = tid >> 6;   // 16 waves
  for (int it = 0; it < KK; ++it) {
    float bvv = -FLT_MAX; int bii = 0x7fffffff;
    #pragma unroll
    for (int c = 0; c < 4; ++c)
      if (svv[c] > bvv || (svv[c] == bvv && sii[c] < bii)) { bvv = svv[c]; bii = sii[c]; }
    #pragma unroll
    for (int off = 1; off < 64; off <<= 1) {
      const float ov = __shfl_xor(bvv, off);
      const int   oi = __shfl_xor(bii, off);
      if (ov > bvv || (ov == bvv && oi < bii)) { bvv = ov; bii = oi; }
    }
    #pragma unroll
    for (int c = 0; c < 4; ++c) if (sii[c] == bii) svv[c] = -FLT_MAX;
    if (lane == 0) { cand_v[wv * KK + it] = bvv; cand_i[wv * KK + it] = bii; }
  }
  __syncthreads();

  // merge 16x45 + softmax (wave 0)
  if (tid < 64) {
    float mv[12]; int mi[12];
    #pragma unroll
    for (int c = 0; c < 12; ++c) {
      const int id = tid + 64 * c;
      if (id < 16 * KK) { mv[c] = cand_v[id]; mi[c] = cand_i[id]; }
      else              { mv[c] = -FLT_MAX;   mi[c] = 0x7fffffff; }
    }
    float m0 = 0.f, sum = 0.f, myv = -FLT_MAX; int myi = 0;
    for (int it = 0; it < KK; ++it) {
      float bvv = -FLT_MAX; int bii = 0x7fffffff;
      #pragma unroll
      for (int c = 0; c < 12; ++c)
        if (mv[c] > bvv || (mv[c] == bvv && mi[c] < bii)) { bvv = mv[c]; bii = mi[c]; }
      #pragma unroll
      for (int off = 1; off < 64; off <<= 1) {
        const float ov = __shfl_xor(bvv, off);
        const int   oi = __shfl_xor(bii, off);
        if (ov > bvv || (ov == bvv && oi < bii)) { bvv = ov; bii = oi; }
      }
      if (it == 0) m0 = bvv;
      sum += expf(bvv - m0);               // identical on all lanes
      if (tid == it) { myv = bvv; myi = bii; }
      #pragma unroll
      for (int c = 0; c < 12; ++c) if (mi[c] == bii) mv[c] = -FLT_MAX;
    }
    if (tid < KK) { w_sh[tid] = expf(myv - m0) / sum; i_sh[tid] = myi; }
  }
  __syncthreads();

  // gather: out[t] = sum_j w_j * v[(idx_j + t) & 4095]
  {
    float acc[4] = {0, 0, 0, 0};
    for (int j = 0; j < KK; ++j) {
      const float wj = w_sh[j];
      const int   bse = i_sh[j] + tid;
      #pragma unroll
      for (int r = 0; r < 4; ++r)
        acc[r] = fmaf(wj, v_lds[(bse + (r << 10)) & (L_ - 1)], acc[r]);
    }
    float* op = outp + ((size_t)bh << 12);
    #pragma unroll
    for (int r = 0; r < 4; ++r) op[tid + (r << 10)] = acc[r];
  }
}

extern "C" void kernel_launch(void* const* d_in, const int* in_sizes, int n_in,
                              void* d_out, int out_size, void* d_ws, size_t ws_size,
                              hipStream_t stream) {
  const float* queries = (const float*)d_in[0];
  const float* keys    = (const float*)d_in[1];
  const float* values  = (const float*)d_in[2];
  const float* Wq = (const float*)d_in[3];
  const float* bq = (const float*)d_in[4];
  const float* Wk = (const float*)d_in[5];
  const float* bk = (const float*)d_in[6];
  const float* Wv = (const float*)d_in[7];
  const float* bv = (const float*)d_in[8];
  float2* ws = (float2*)d_ws;
  float* out = (float*)d_out;

  hipLaunchKernelGGL(setup_tables,  dim3(32), dim3(512), 0, stream, ws);
  hipLaunchKernelGGL(setup_filters, dim3(2),  dim3(512), 0, stream, ws);
  hipLaunchKernelGGL(autocorr_fwd,  dim3(512), dim3(1024), 0, stream,
                     queries, keys, Wq, bq, Wk, bk, ws);
  hipLaunchKernelGGL(autocorr_inv,  dim3(256), dim3(1024), 0, stream,
                     values, Wv, bv, ws, out);
}

// Round 16
// 330.773 us; speedup vs baseline: 1.0998x; 1.0998x over previous
//
#include <hip/hip_runtime.h>
#include <math.h>
#include <float.h>

#define L_   4096
#define M_   8192
#define H_   8
#define D_   64
#define KK   45          // 5 * ceil(ln(4096))

// ws layout in float2 units
#define WS_C   0         // c[4096]  : e^{-i pi j^2 / 8191}
#define WS_D   4096      // d[4096]  : e^{+i pi j^2 / 8190}
#define WS_TW  8192      // tw[8192] : e^{-2 pi i j / 8192} (fp64-accurate; setup_filters only)
#define WS_H1  16384     // H1s[8192]: radix4-DIF(conj-chirp c), pre-scaled 1/8192, digit-reversed
#define WS_H2  24576     // H2s[8192]: same for d
#define WS_QKV 32768     // float2 offset where staged q/k/v planes start
// tables: 256 KB; then q/k/v planes: 3 x 1M floats = 12 MB

typedef unsigned int u32_t;

__device__ __forceinline__ float2 cadd(float2 a, float2 b) { return make_float2(a.x + b.x, a.y + b.y); }
__device__ __forceinline__ float2 csub(float2 a, float2 b) { return make_float2(a.x - b.x, a.y - b.y); }
__device__ __forceinline__ float2 cmulf(float2 a, float2 b) {
  return make_float2(a.x * b.x - a.y * b.y, a.x * b.y + a.y * b.x);
}
__device__ __forceinline__ float2 cmulcf(float2 a, float2 b) {  // a * conj(b)
  return make_float2(a.x * b.x + a.y * b.y, a.y * b.x - a.x * b.y);
}

// register twiddle: e^{-2 pi i e / 8192}, e in [0, 2048)
__device__ __forceinline__ float2 twf(int e) {
  float s, c;
  __sincosf((float)e * -7.66990394e-4f, &s, &c);   // -2*pi/8192
  return make_float2(c, s);
}

#define R4DIF(BUF) { \
  const float2 a = BUF[i0], b = BUF[i0 + q], c = BUF[i0 + 2 * q], d = BUF[i0 + 3 * q]; \
  const float2 t0 = cadd(a, c), t1 = csub(a, c), t2 = cadd(b, d), t3 = csub(b, d); \
  BUF[i0]         = cadd(t0, t2); \
  BUF[i0 + q]     = cmulf(make_float2(t1.x + t3.y, t1.y - t3.x), w1); \
  BUF[i0 + 2 * q] = cmulf(csub(t0, t2), w2); \
  BUF[i0 + 3 * q] = cmulf(make_float2(t1.x - t3.y, t1.y + t3.x), w3); }

#define R4DIT(BUF) { \
  const float2 z0 = BUF[i0]; \
  const float2 z1 = cmulcf(BUF[i0 + q],     w1); \
  const float2 z2 = cmulcf(BUF[i0 + 2 * q], w2); \
  const float2 z3 = cmulcf(BUF[i0 + 3 * q], w3); \
  const float2 t0 = cadd(z0, z2), t1 = csub(z0, z2), t2 = cadd(z1, z3), u = csub(z1, z3); \
  BUF[i0]         = cadd(t0, t2); \
  BUF[i0 + q]     = make_float2(t1.x - u.y, t1.y + u.x); \
  BUF[i0 + 2 * q] = csub(t0, t2); \
  BUF[i0 + 3 * q] = make_float2(t1.x + u.y, t1.y - u.x); }

// register-array radix-4 butterflies (all indices compile-time at call sites)
__device__ __forceinline__ void bfly4_dif(float2 x[4], float2 w1, float2 w2, float2 w3) {
  const float2 t0 = cadd(x[0], x[2]), t1 = csub(x[0], x[2]);
  const float2 t2 = cadd(x[1], x[3]), t3 = csub(x[1], x[3]);
  x[0] = cadd(t0, t2);
  x[1] = cmulf(make_float2(t1.x + t3.y, t1.y - t3.x), w1);
  x[2] = cmulf(csub(t0, t2), w2);
  x[3] = cmulf(make_float2(t1.x - t3.y, t1.y + t3.x), w3);
}
__device__ __forceinline__ void bfly4_dit(float2 x[4], float2 w1, float2 w2, float2 w3) {
  const float2 z0 = x[0];
  const float2 z1 = cmulcf(x[1], w1);
  const float2 z2 = cmulcf(x[2], w2);
  const float2 z3 = cmulcf(x[3], w3);
  const float2 t0 = cadd(z0, z2), t1 = csub(z0, z2), t2 = cadd(z1, z3), u = csub(z1, z3);
  x[0] = cadd(t0, t2);
  x[1] = make_float2(t1.x - u.y, t1.y + u.x);
  x[2] = csub(t0, t2);
  x[3] = make_float2(t1.x + u.y, t1.y - u.x);
}

// fused r2 + H-pointwise + r2inv on one float2-pair packed in a float4
__device__ __forceinline__ float4 midpair(float4 a, float4 h) {
  float2 u = make_float2(a.x + a.z, a.y + a.w);
  float2 v = make_float2(a.x - a.z, a.y - a.w);
  u = cmulf(u, make_float2(h.x, h.y));
  v = cmulf(v, make_float2(h.z, h.w));
  return make_float4(u.x + v.x, u.y + v.y, u.x - v.x, u.y - v.y);
}

// middle forward stages s=1..5 on two buffers (1024 threads)
static __device__ void fwd_stages2(float2* A, float2* B) {
  const int tid = threadIdx.x;
  #pragma unroll
  for (int s = 1; s < 6; ++s) {
    const int q = 2048 >> (2 * s);
    __syncthreads();
    #pragma unroll
    for (int r = 0; r < 2; ++r) {
      const int bid = tid + (r << 10);
      const int j   = bid & (q - 1);
      const int i0  = ((bid >> (11 - 2 * s)) << (13 - 2 * s)) + j;
      const float2 w1 = twf(j << (2 * s));
      const float2 w2 = cmulf(w1, w1);
      const float2 w3 = cmulf(w2, w1);
      R4DIF(A) R4DIF(B)
    }
  }
}
static __device__ void inv_stages2(float2* A, float2* B) {   // s=5..1
  const int tid = threadIdx.x;
  #pragma unroll
  for (int s = 5; s >= 1; --s) {
    const int q = 2048 >> (2 * s);
    __syncthreads();
    #pragma unroll
    for (int r = 0; r < 2; ++r) {
      const int bid = tid + (r << 10);
      const int j   = bid & (q - 1);
      const int i0  = ((bid >> (11 - 2 * s)) << (13 - 2 * s)) + j;
      const float2 w1 = twf(j << (2 * s));
      const float2 w2 = cmulf(w1, w1);
      const float2 w3 = cmulf(w2, w1);
      R4DIT(A) R4DIT(B)
    }
  }
}
static __device__ void fwd_stages1(float2* A) {
  const int tid = threadIdx.x;
  #pragma unroll
  for (int s = 1; s < 6; ++s) {
    const int q = 2048 >> (2 * s);
    __syncthreads();
    #pragma unroll
    for (int r = 0; r < 2; ++r) {
      const int bid = tid + (r << 10);
      const int j   = bid & (q - 1);
      const int i0  = ((bid >> (11 - 2 * s)) << (13 - 2 * s)) + j;
      const float2 w1 = twf(j << (2 * s));
      const float2 w2 = cmulf(w1, w1);
      const float2 w3 = cmulf(w2, w1);
      R4DIF(A)
    }
  }
}
static __device__ void inv_stages1(float2* A) {
  const int tid = threadIdx.x;
  #pragma unroll
  for (int s = 5; s >= 1; --s) {
    const int q = 2048 >> (2 * s);
    __syncthreads();
    #pragma unroll
    for (int r = 0; r < 2; ++r) {
      const int bid = tid + (r << 10);
      const int j   = bid & (q - 1);
      const int i0  = ((bid >> (11 - 2 * s)) << (13 - 2 * s)) + j;
      const float2 w1 = twf(j << (2 * s));
      const float2 w2 = cmulf(w1, w1);
      const float2 w3 = cmulf(w2, w1);
      R4DIT(A)
    }
  }
}

// ---------------- setup: tables (fp64) + Bluestein filters ----------------
template <int NT>
static __device__ void fft_dif_tab(float2* buf, const float2* __restrict__ tw) {
  const int tid = threadIdx.x;
  for (int s = 0; s < 6; ++s) {
    const int q = 2048 >> (2 * s);
    __syncthreads();
    for (int r = 0; r < 2048 / NT; ++r) {
      const int bid = tid + r * NT;
      const int j   = bid & (q - 1);
      const int i0  = ((bid >> (11 - 2 * s)) << (13 - 2 * s)) + j;
      const int e   = j << (2 * s);
      const float2 w1 = tw[e], w2 = tw[2 * e], w3 = tw[3 * e];
      R4DIF(buf)
    }
  }
  __syncthreads();
  for (int r = 0; r < 4096 / NT; ++r) {
    const int i0 = (tid + r * NT) << 1;
    const float2 a = buf[i0], b = buf[i0 + 1];
    buf[i0] = cadd(a, b); buf[i0 + 1] = csub(a, b);
  }
  __syncthreads();
}

extern "C" __global__ void setup_tables(float2* ws) {
  const int idx = blockIdx.x * 512 + threadIdx.x;
  if (idx < 4096) {
    const long p = ((long)idx * idx) % 16382;      // j^2 mod 2*8191
    const double th = -M_PI * (double)p / 8191.0;
    double s, c; sincos(th, &s, &c);
    ws[WS_C + idx] = make_float2((float)c, (float)s);
  } else if (idx < 8192) {
    const int j = idx - 4096;
    const long p = ((long)j * j) % 16380;          // j^2 mod 2*8190
    const double th = M_PI * (double)p / 8190.0;
    double s, c; sincos(th, &s, &c);
    ws[WS_D + j] = make_float2((float)c, (float)s);
  } else if (idx < 16384) {
    const int j = idx - 8192;
    const double th = -M_PI * (double)j / 4096.0;  // e^{-2pi i j/8192}
    double s, c; sincos(th, &s, &c);
    ws[WS_TW + j] = make_float2((float)c, (float)s);
  }
}

extern "C" __global__ __launch_bounds__(512, 1) void setup_filters(float2* ws) {
  __shared__ __align__(16) float2 buf[M_];
  const float2* src = ws + (blockIdx.x == 0 ? WS_C : WS_D);
  float2*       dst = ws + (blockIdx.x == 0 ? WS_H1 : WS_H2);
  const float2* tw  = ws + WS_TW;
  for (int i = threadIdx.x; i < M_; i += 512) {
    float2 val = make_float2(0.f, 0.f);
    if (i != 4096) {                       // kernel support |j| <= 4095
      const int jj = (i <= 4095) ? i : (M_ - i);   // chirp is even in j
      const float2 e = src[jj];
      val = make_float2(e.x, -e.y);        // conj(chirp)
    }
    buf[i] = val;
  }
  fft_dif_tab<512>(buf, tw);
  const float sc = 1.0f / 8192.0f;         // fold IFFT scaling into the filter
  for (int i = threadIdx.x; i < M_; i += 512)
    dst[i] = make_float2(buf[i].x * sc, buf[i].y * sc);
}

// ---------------- projection kernel v4: global_load_lds deep-pipelined streaming ----------
// Block = 256 thr (4 waves). Each wave owns a private 2x4KB LDS double buffer and streams
// 2-row (1024-float) tiles: issue 4 global_load_lds (1KB each, stays in flight across
// iters), counted s_waitcnt vmcnt(N), ds_read_b128 consume, 16-lane shfl dot-reduce.
// No __syncthreads in the stream loop (wave-private tiles) -> no vmcnt(0) drain.
// In-flight per wave = 8 KB; per CU (5 blocks by LDS) ~160 KB >> latency-BW product.
__device__ __forceinline__ void gll16(const float* gsrc, float* ldsbase) {
  __builtin_amdgcn_global_load_lds(
      (const __attribute__((address_space(1))) u32_t*)gsrc,
      (__attribute__((address_space(3))) u32_t*)ldsbase, 16, 0, 0);
}

extern "C" __global__ __launch_bounds__(256)
void proj_kernel(const float* __restrict__ queries, const float* __restrict__ keys,
                 const float* __restrict__ values,
                 const float* __restrict__ Wq, const float* __restrict__ bq,
                 const float* __restrict__ Wk, const float* __restrict__ bk,
                 const float* __restrict__ Wv, const float* __restrict__ bv,
                 float* __restrict__ q_ws, float* __restrict__ k_ws,
                 float* __restrict__ v_ws)
{
  __shared__ __align__(16) float lds[4][2][1024];   // 32 KB: wave x dbuf x tile

  const int tid  = threadIdx.x;
  const int w    = tid >> 6;
  const int lane = tid & 63;
  const int q16  = lane & 15;          // d-quad within a 64-float head
  const int hi   = lane >> 4;          // head-subgroup 0..3
  const int blk  = blockIdx.x;         // 2048 blocks
  const int b    = blk >> 6;           // 0..31
  const int b8   = b * 8;
  const int lbase = (blk & 63) << 6;   // 64 rows per block

  const float* bases[3] = { queries + (size_t)b * 2097152,
                            keys    + (size_t)b * 2097152,
                            values  + (size_t)b * 2097152 };
  float* dsts[3] = { q_ws, k_ws, v_ws };
  const float4 wv4[3] = { reinterpret_cast<const float4*>(Wq)[q16],
                          reinterpret_cast<const float4*>(Wk)[q16],
                          reinterpret_cast<const float4*>(Wv)[q16] };
  const float bias3[3] = { bq[0], bk[0], bv[0] };

  // iter IT = s*8 + i: input s, rows l0 = lbase + (i*4 + w)*2 (rows l0, l0+1)
#define PR_SRC(IT) (bases[(IT) >> 3] + (size_t)(lbase + ((((IT) & 7) << 2) + w) * 2) * 512)
#define PR_ISSUE(IT) { \
    const float* g_ = PR_SRC(IT); \
    float* l_ = lds[w][(IT) & 1]; \
    gll16(g_ + 0 * 256 + lane * 4, l_ + 0 * 256); \
    gll16(g_ + 1 * 256 + lane * 4, l_ + 1 * 256); \
    gll16(g_ + 2 * 256 + lane * 4, l_ + 2 * 256); \
    gll16(g_ + 3 * 256 + lane * 4, l_ + 3 * 256); }

  PR_ISSUE(0)
  #pragma unroll
  for (int it = 0; it < 24; ++it) {
    if (it + 1 < 24) { PR_ISSUE(it + 1) }
    // counted wait: the (up to) 8 newest vm-ops are stores(it-1) + gll(it+1);
    // everything older (incl. gll(it)) must retire.
    if (it == 0)           { asm volatile("s_waitcnt vmcnt(4)" ::: "memory"); }
    else if (it + 1 < 24)  { asm volatile("s_waitcnt vmcnt(8)" ::: "memory"); }
    else                   { asm volatile("s_waitcnt vmcnt(4)" ::: "memory"); }
    const int s_ = it >> 3;
    const float* L = lds[w][it & 1];
    const float4 wq_ = wv4[s_];
    // read j: floats [j*256 + lane*4, +4)  -> row j>>1, head (j&1)*4 + hi, quad q16
    float dj[4];
    #pragma unroll
    for (int j = 0; j < 4; ++j) {
      const float4 x = *reinterpret_cast<const float4*>(L + j * 256 + lane * 4);
      dj[j] = x.x * wq_.x + x.y * wq_.y + x.z * wq_.z + x.w * wq_.w;
    }
    #pragma unroll
    for (int j = 0; j < 4; ++j) {
      dj[j] += __shfl_xor(dj[j], 1);
      dj[j] += __shfl_xor(dj[j], 2);
      dj[j] += __shfl_xor(dj[j], 4);
      dj[j] += __shfl_xor(dj[j], 8);
    }
    if (q16 == 0) {
      const int l0 = lbase + (((it & 7) << 2) + w) * 2;
      float* dst = dsts[s_];
      const float bias = bias3[s_];
      #pragma unroll
      for (int j = 0; j < 4; ++j) {
        const int h = ((j & 1) << 2) + hi;
        dst[((size_t)(b8 + h) << 12) + l0 + (j >> 1)] = dj[j] + bias;
      }
    }
  }
#undef PR_ISSUE
#undef PR_SRC
}

// ---------------- main kernel: radix-4 CZT with register-fused stage-0 passes (r13) ------
extern "C" __global__ __launch_bounds__(1024, 1)
void autocorr_main(const float2* __restrict__ ws,
                   const float* __restrict__ q_ws, const float* __restrict__ k_ws,
                   const float* __restrict__ v_ws, float* __restrict__ outp)
{
  __shared__ __align__(16) float2 bufA[M_];   // 64 KB (K path, then inverse-CZT)
  __shared__ __align__(16) float2 bufB[M_];   // 64 KB (Q path)
  __shared__ float  v_lds[L_];                // 16 KB
  __shared__ float  cand_v[16 * KK];
  __shared__ int    cand_i[16 * KK];
  __shared__ float  w_sh[KK];
  __shared__ int    i_sh[KK];

  const int tid = threadIdx.x;
  const int bh  = blockIdx.x;

  const float2* c_t = ws + WS_C;
  const float2* d_t = ws + WS_D;
  const float2* H1  = ws + WS_H1;
  const float2* H2  = ws + WS_H2;
  const float* qrow = q_ws + ((size_t)bh << 12);
  const float* krow = k_ws + ((size_t)bh << 12);
  const float* vrow = v_ws + ((size_t)bh << 12);

  // v into LDS (consumed only after many barriers)
  {
    const float4 v4 = reinterpret_cast<const float4*>(vrow)[tid];
    reinterpret_cast<float4*>(v_lds)[tid] = v4;
  }

  // ======== ENTRY FUSION: chirp-premultiply + conv2 forward s=0 (q=2048), registers ======
  #pragma unroll
  for (int r = 0; r < 2; ++r) {
    const int bid = tid + (r << 10);                 // j = i0 = bid (< 2048)
    const float2 w1 = twf(bid);
    const float2 w2 = cmulf(w1, w1);
    const float2 w3 = cmulf(w2, w1);
    const float2 cc0 = c_t[bid], cc1 = c_t[bid + 2048];
    const float k0 = krow[bid], k1 = krow[bid + 2048];
    const float q0 = qrow[bid], q1 = qrow[bid + 2048];
    float2 xa[4] = { make_float2(k0 * cc0.x, k0 * cc0.y),
                     make_float2(k1 * cc1.x, k1 * cc1.y),
                     make_float2(0.f, 0.f), make_float2(0.f, 0.f) };
    float2 xb[4] = { make_float2(q0 * cc0.x, q0 * cc0.y),
                     make_float2(q1 * cc1.x, q1 * cc1.y),
                     make_float2(0.f, 0.f), make_float2(0.f, 0.f) };
    bfly4_dif(xa, w1, w2, w3);
    bfly4_dif(xb, w1, w2, w3);
    #pragma unroll
    for (int k = 0; k < 4; ++k) {
      bufA[bid + k * 2048] = xa[k];
      bufB[bid + k * 2048] = xb[k];
    }
  }

  // conv2 middle: fwd s=1..5, midpair(H1), inv s=5..1
  fwd_stages2(bufA, bufB);
  __syncthreads();
  #pragma unroll
  for (int r = 0; r < 4; ++r) {
    const int p = tid + (r << 10);
    const float4 h = reinterpret_cast<const float4*>(H1)[p];
    reinterpret_cast<float4*>(bufA)[p] = midpair(reinterpret_cast<float4*>(bufA)[p], h);
    reinterpret_cast<float4*>(bufB)[p] = midpair(reinterpret_cast<float4*>(bufB)[p], h);
  }
  inv_stages2(bufA, bufB);
  __syncthreads();

  // ======== MIDDLE FUSION: conv2 inv s=0 + F-build + g.d + conv1 fwd s=0, registers =====
  {
    float2 gd[2][2];
    #pragma unroll
    for (int r = 0; r < 2; ++r) {
      const int bid = tid + (r << 10);
      const float2 w1 = twf(bid);
      const float2 w2 = cmulf(w1, w1);
      const float2 w3 = cmulf(w2, w1);
      float2 xa[4], xb[4];
      #pragma unroll
      for (int k = 0; k < 4; ++k) { xa[k] = bufA[bid + k * 2048]; xb[k] = bufB[bid + k * 2048]; }
      bfly4_dit(xa, w1, w2, w3);
      bfly4_dit(xb, w1, w2, w3);
      #pragma unroll
      for (int k = 0; k < 2; ++k) {                  // k>=2 are pad outputs: discarded
        const int m = bid + k * 2048;
        const float2 cc = c_t[m];
        const float2 K = cmulf(cc, xa[k]);
        const float2 Q = cmulf(cc, xb[k]);
        const float2 F = cmulcf(Q, K);
        float2 g;
        if (m == 0 || m == 4095) g = make_float2(F.x, 0.f);   // DC/Nyquist: Im dropped
        else                     g = make_float2(2.f * F.x, 2.f * F.y);
        gd[r][k] = cmulf(g, d_t[m]);
      }
    }
    #pragma unroll
    for (int r = 0; r < 2; ++r) {
      const int bid = tid + (r << 10);
      const float2 w1 = twf(bid);
      const float2 w2 = cmulf(w1, w1);
      const float2 w3 = cmulf(w2, w1);
      float2 x[4] = { gd[r][0], gd[r][1], make_float2(0.f, 0.f), make_float2(0.f, 0.f) };
      bfly4_dif(x, w1, w2, w3);
      #pragma unroll
      for (int k = 0; k < 4; ++k) bufA[bid + k * 2048] = x[k];
    }
  }

  // conv1 middle: fwd s=1..5, midpair(H2), inv s=5..1
  fwd_stages1(bufA);
  __syncthreads();
  #pragma unroll
  for (int r = 0; r < 4; ++r) {
    const int p = tid + (r << 10);
    const float4 h = reinterpret_cast<const float4*>(H2)[p];
    reinterpret_cast<float4*>(bufA)[p] = midpair(reinterpret_cast<float4*>(bufA)[p], h);
  }
  inv_stages1(bufA);
  __syncthreads();

  // ======== EXIT FUSION: conv1 inv s=0 + score, registers ========
  const float SCALE = (float)(1.0 / (8190.0 * 4096.0));   // /8190 (irfft) then /4096 (L)
  float svv[4]; int sii[4];
  #pragma unroll
  for (int r = 0; r < 2; ++r) {
    const int bid = tid + (r << 10);
    const float2 w1 = twf(bid);
    const float2 w2 = cmulf(w1, w1);
    const float2 w3 = cmulf(w2, w1);
    float2 x[4];
    #pragma unroll
    for (int k = 0; k < 4; ++k) x[k] = bufA[bid + k * 2048];
    bfly4_dit(x, w1, w2, w3);
    #pragma unroll
    for (int k = 0; k < 2; ++k) {                    // k>=2 are pad outputs: discarded
      const int t = bid + k * 2048;
      const float2 Z = cmulf(d_t[t], x[k]);
      svv[2 * r + k] = Z.x * SCALE;
      sii[2 * r + k] = t;
    }
  }

  // ---------------- per-wave top-45 ----------------
  const int lane = tid & 63, wv = tid >> 6;   // 16 waves
  for (int it = 0; it < KK; ++it) {
    float bvv = -FLT_MAX; int bii = 0x7fffffff;
    #pragma unroll
    for (int c = 0; c < 4; ++c)
      if (svv[c] > bvv || (svv[c] == bvv && sii[c] < bii)) { bvv = svv[c]; bii = sii[c]; }
    #pragma unroll
    for (int off = 1; off < 64; off <<= 1) {
      const float ov = __shfl_xor(bvv, off);
      const int   oi = __shfl_xor(bii, off);
      if (ov > bvv || (ov == bvv && oi < bii)) { bvv = ov; bii = oi; }
    }
    #pragma unroll
    for (int c = 0; c < 4; ++c) if (sii[c] == bii) svv[c] = -FLT_MAX;
    if (lane == 0) { cand_v[wv * KK + it] = bvv; cand_i[wv * KK + it] = bii; }
  }
  __syncthreads();

  // ---------------- merge 16x45 + softmax (wave 0) ----------------
  if (tid < 64) {
    float mv[12]; int mi[12];
    #pragma unroll
    for (int c = 0; c < 12; ++c) {
      const int id = tid + 64 * c;
      if (id < 16 * KK) { mv[c] = cand_v[id]; mi[c] = cand_i[id]; }
      else              { mv[c] = -FLT_MAX;   mi[c] = 0x7fffffff; }
    }
    float m0 = 0.f, sum = 0.f, myv = -FLT_MAX; int myi = 0;
    for (int it = 0; it < KK; ++it) {
      float bvv = -FLT_MAX; int bii = 0x7fffffff;
      #pragma unroll
      for (int c = 0; c < 12; ++c)
        if (mv[c] > bvv || (mv[c] == bvv && mi[c] < bii)) { bvv = mv[c]; bii = mi[c]; }
      #pragma unroll
      for (int off = 1; off < 64; off <<= 1) {
        const float ov = __shfl_xor(bvv, off);
        const int   oi = __shfl_xor(bii, off);
        if (ov > bvv || (ov == bvv && oi < bii)) { bvv = ov; bii = oi; }
      }
      if (it == 0) m0 = bvv;
      sum += expf(bvv - m0);               // identical on all lanes
      if (tid == it) { myv = bvv; myi = bii; }
      #pragma unroll
      for (int c = 0; c < 12; ++c) if (mi[c] == bii) mv[c] = -FLT_MAX;
    }
    if (tid < KK) { w_sh[tid] = expf(myv - m0) / sum; i_sh[tid] = myi; }
  }
  __syncthreads();

  // ---------------- gather: out[t] = sum_j w_j * v[(idx_j + t) & 4095] ------------
  {
    float acc[4] = {0, 0, 0, 0};
    for (int j = 0; j < KK; ++j) {
      const float wj = w_sh[j];
      const int   bse = i_sh[j] + tid;
      #pragma unroll
      for (int r = 0; r < 4; ++r)
        acc[r] = fmaf(wj, v_lds[(bse + (r << 10)) & (L_ - 1)], acc[r]);
    }
    float* op = outp + ((size_t)bh << 12);
    #pragma unroll
    for (int r = 0; r < 4; ++r) op[tid + (r << 10)] = acc[r];
  }
}

extern "C" void kernel_launch(void* const* d_in, const int* in_sizes, int n_in,
                              void* d_out, int out_size, void* d_ws, size_t ws_size,
                              hipStream_t stream) {
  const float* queries = (const float*)d_in[0];
  const float* keys    = (const float*)d_in[1];
  const float* values  = (const float*)d_in[2];
  const float* Wq = (const float*)d_in[3];
  const float* bq = (const float*)d_in[4];
  const float* Wk = (const float*)d_in[5];
  const float* bk = (const float*)d_in[6];
  const float* Wv = (const float*)d_in[7];
  const float* bv = (const float*)d_in[8];
  float2* ws = (float2*)d_ws;
  float* q_ws = (float*)d_ws + 2 * WS_QKV;
  float* k_ws = q_ws + (1 << 20);
  float* v_ws = k_ws + (1 << 20);
  float* out = (float*)d_out;

  hipLaunchKernelGGL(setup_tables,  dim3(32), dim3(512), 0, stream, ws);
  hipLaunchKernelGGL(setup_filters, dim3(2),  dim3(512), 0, stream, ws);
  hipLaunchKernelGGL(proj_kernel,   dim3(2048), dim3(256), 0, stream,
                     queries, keys, values, Wq, bq, Wk, bk, Wv, bv, q_ws, k_ws, v_ws);
  hipLaunchKernelGGL(autocorr_main, dim3(256), dim3(1024), 0, stream,
                     ws, q_ws, k_ws, v_ws, out);
}

// Round 17
// 320.688 us; speedup vs baseline: 1.1343x; 1.0314x over previous
//
#include <hip/hip_runtime.h>
#include <math.h>
#include <float.h>

#define L_   4096
#define M_   8192
#define H_   8
#define D_   64
#define KK   45          // 5 * ceil(ln(4096))

// ws layout in float2 units
#define WS_C   0         // c[4096]  : e^{-i pi j^2 / 8191}
#define WS_D   4096      // d[4096]  : e^{+i pi j^2 / 8190}
#define WS_TW  8192      // tw[8192] : e^{-2 pi i j / 8192} (fp64-accurate; setup_filters only)
#define WS_H1  16384     // H1s[8192]: radix4-DIF(conj-chirp c), pre-scaled 1/8192, digit-reversed
#define WS_H2  24576     // H2s[8192]: same for d
#define WS_QKV 32768     // float2 offset where staged q/k/v planes start
// tables: 256 KB; then q/k/v planes: 3 x 1M floats = 12 MB

typedef unsigned int u32_t;

__device__ __forceinline__ float2 cadd(float2 a, float2 b) { return make_float2(a.x + b.x, a.y + b.y); }
__device__ __forceinline__ float2 csub(float2 a, float2 b) { return make_float2(a.x - b.x, a.y - b.y); }
__device__ __forceinline__ float2 cmulf(float2 a, float2 b) {
  return make_float2(a.x * b.x - a.y * b.y, a.x * b.y + a.y * b.x);
}
__device__ __forceinline__ float2 cmulcf(float2 a, float2 b) {  // a * conj(b)
  return make_float2(a.x * b.x + a.y * b.y, a.y * b.x - a.x * b.y);
}

// register twiddle: e^{-2 pi i e / 8192}, e in [0, 2048)
__device__ __forceinline__ float2 twf(int e) {
  float s, c;
  __sincosf((float)e * -7.66990394e-4f, &s, &c);   // -2*pi/8192
  return make_float2(c, s);
}

#define R4DIF(BUF) { \
  const float2 a = BUF[i0], b = BUF[i0 + q], c = BUF[i0 + 2 * q], d = BUF[i0 + 3 * q]; \
  const float2 t0 = cadd(a, c), t1 = csub(a, c), t2 = cadd(b, d), t3 = csub(b, d); \
  BUF[i0]         = cadd(t0, t2); \
  BUF[i0 + q]     = cmulf(make_float2(t1.x + t3.y, t1.y - t3.x), w1); \
  BUF[i0 + 2 * q] = cmulf(csub(t0, t2), w2); \
  BUF[i0 + 3 * q] = cmulf(make_float2(t1.x - t3.y, t1.y + t3.x), w3); }

#define R4DIT(BUF) { \
  const float2 z0 = BUF[i0]; \
  const float2 z1 = cmulcf(BUF[i0 + q],     w1); \
  const float2 z2 = cmulcf(BUF[i0 + 2 * q], w2); \
  const float2 z3 = cmulcf(BUF[i0 + 3 * q], w3); \
  const float2 t0 = cadd(z0, z2), t1 = csub(z0, z2), t2 = cadd(z1, z3), u = csub(z1, z3); \
  BUF[i0]         = cadd(t0, t2); \
  BUF[i0 + q]     = make_float2(t1.x - u.y, t1.y + u.x); \
  BUF[i0 + 2 * q] = csub(t0, t2); \
  BUF[i0 + 3 * q] = make_float2(t1.x + u.y, t1.y - u.x); }

// register-array radix-4 butterflies (all indices compile-time at call sites)
__device__ __forceinline__ void bfly4_dif(float2 x[4], float2 w1, float2 w2, float2 w3) {
  const float2 t0 = cadd(x[0], x[2]), t1 = csub(x[0], x[2]);
  const float2 t2 = cadd(x[1], x[3]), t3 = csub(x[1], x[3]);
  x[0] = cadd(t0, t2);
  x[1] = cmulf(make_float2(t1.x + t3.y, t1.y - t3.x), w1);
  x[2] = cmulf(csub(t0, t2), w2);
  x[3] = cmulf(make_float2(t1.x - t3.y, t1.y + t3.x), w3);
}
__device__ __forceinline__ void bfly4_dit(float2 x[4], float2 w1, float2 w2, float2 w3) {
  const float2 z0 = x[0];
  const float2 z1 = cmulcf(x[1], w1);
  const float2 z2 = cmulcf(x[2], w2);
  const float2 z3 = cmulcf(x[3], w3);
  const float2 t0 = cadd(z0, z2), t1 = csub(z0, z2), t2 = cadd(z1, z3), u = csub(z1, z3);
  x[0] = cadd(t0, t2);
  x[1] = make_float2(t1.x - u.y, t1.y + u.x);
  x[2] = csub(t0, t2);
  x[3] = make_float2(t1.x + u.y, t1.y - u.x);
}

// fused r2 + H-pointwise + r2inv on one float2-pair packed in a float4
__device__ __forceinline__ float4 midpair(float4 a, float4 h) {
  float2 u = make_float2(a.x + a.z, a.y + a.w);
  float2 v = make_float2(a.x - a.z, a.y - a.w);
  u = cmulf(u, make_float2(h.x, h.y));
  v = cmulf(v, make_float2(h.z, h.w));
  return make_float4(u.x + v.x, u.y + v.y, u.x - v.x, u.y - v.y);
}

// middle forward stages s=1..5 on two buffers (1024 threads)
static __device__ void fwd_stages2(float2* A, float2* B) {
  const int tid = threadIdx.x;
  #pragma unroll
  for (int s = 1; s < 6; ++s) {
    const int q = 2048 >> (2 * s);
    __syncthreads();
    #pragma unroll
    for (int r = 0; r < 2; ++r) {
      const int bid = tid + (r << 10);
      const int j   = bid & (q - 1);
      const int i0  = ((bid >> (11 - 2 * s)) << (13 - 2 * s)) + j;
      const float2 w1 = twf(j << (2 * s));
      const float2 w2 = cmulf(w1, w1);
      const float2 w3 = cmulf(w2, w1);
      R4DIF(A) R4DIF(B)
    }
  }
}
static __device__ void inv_stages2(float2* A, float2* B) {   // s=5..1
  const int tid = threadIdx.x;
  #pragma unroll
  for (int s = 5; s >= 1; --s) {
    const int q = 2048 >> (2 * s);
    __syncthreads();
    #pragma unroll
    for (int r = 0; r < 2; ++r) {
      const int bid = tid + (r << 10);
      const int j   = bid & (q - 1);
      const int i0  = ((bid >> (11 - 2 * s)) << (13 - 2 * s)) + j;
      const float2 w1 = twf(j << (2 * s));
      const float2 w2 = cmulf(w1, w1);
      const float2 w3 = cmulf(w2, w1);
      R4DIT(A) R4DIT(B)
    }
  }
}
static __device__ void fwd_stages1(float2* A) {
  const int tid = threadIdx.x;
  #pragma unroll
  for (int s = 1; s < 6; ++s) {
    const int q = 2048 >> (2 * s);
    __syncthreads();
    #pragma unroll
    for (int r = 0; r < 2; ++r) {
      const int bid = tid + (r << 10);
      const int j   = bid & (q - 1);
      const int i0  = ((bid >> (11 - 2 * s)) << (13 - 2 * s)) + j;
      const float2 w1 = twf(j << (2 * s));
      const float2 w2 = cmulf(w1, w1);
      const float2 w3 = cmulf(w2, w1);
      R4DIF(A)
    }
  }
}
static __device__ void inv_stages1(float2* A) {
  const int tid = threadIdx.x;
  #pragma unroll
  for (int s = 5; s >= 1; --s) {
    const int q = 2048 >> (2 * s);
    __syncthreads();
    #pragma unroll
    for (int r = 0; r < 2; ++r) {
      const int bid = tid + (r << 10);
      const int j   = bid & (q - 1);
      const int i0  = ((bid >> (11 - 2 * s)) << (13 - 2 * s)) + j;
      const float2 w1 = twf(j << (2 * s));
      const float2 w2 = cmulf(w1, w1);
      const float2 w3 = cmulf(w2, w1);
      R4DIT(A)
    }
  }
}

// ---------------- setup: tables (fp64) + Bluestein filters ----------------
template <int NT>
static __device__ void fft_dif_tab(float2* buf, const float2* __restrict__ tw) {
  const int tid = threadIdx.x;
  for (int s = 0; s < 6; ++s) {
    const int q = 2048 >> (2 * s);
    __syncthreads();
    for (int r = 0; r < 2048 / NT; ++r) {
      const int bid = tid + r * NT;
      const int j   = bid & (q - 1);
      const int i0  = ((bid >> (11 - 2 * s)) << (13 - 2 * s)) + j;
      const int e   = j << (2 * s);
      const float2 w1 = tw[e], w2 = tw[2 * e], w3 = tw[3 * e];
      R4DIF(buf)
    }
  }
  __syncthreads();
  for (int r = 0; r < 4096 / NT; ++r) {
    const int i0 = (tid + r * NT) << 1;
    const float2 a = buf[i0], b = buf[i0 + 1];
    buf[i0] = cadd(a, b); buf[i0 + 1] = csub(a, b);
  }
  __syncthreads();
}

extern "C" __global__ void setup_tables(float2* ws) {
  const int idx = blockIdx.x * 512 + threadIdx.x;
  if (idx < 4096) {
    const long p = ((long)idx * idx) % 16382;      // j^2 mod 2*8191
    const double th = -M_PI * (double)p / 8191.0;
    double s, c; sincos(th, &s, &c);
    ws[WS_C + idx] = make_float2((float)c, (float)s);
  } else if (idx < 8192) {
    const int j = idx - 4096;
    const long p = ((long)j * j) % 16380;          // j^2 mod 2*8190
    const double th = M_PI * (double)p / 8190.0;
    double s, c; sincos(th, &s, &c);
    ws[WS_D + j] = make_float2((float)c, (float)s);
  } else if (idx < 16384) {
    const int j = idx - 8192;
    const double th = -M_PI * (double)j / 4096.0;  // e^{-2pi i j/8192}
    double s, c; sincos(th, &s, &c);
    ws[WS_TW + j] = make_float2((float)c, (float)s);
  }
}

extern "C" __global__ __launch_bounds__(512, 1) void setup_filters(float2* ws) {
  __shared__ __align__(16) float2 buf[M_];
  const float2* src = ws + (blockIdx.x == 0 ? WS_C : WS_D);
  float2*       dst = ws + (blockIdx.x == 0 ? WS_H1 : WS_H2);
  const float2* tw  = ws + WS_TW;
  for (int i = threadIdx.x; i < M_; i += 512) {
    float2 val = make_float2(0.f, 0.f);
    if (i != 4096) {                       // kernel support |j| <= 4095
      const int jj = (i <= 4095) ? i : (M_ - i);   // chirp is even in j
      const float2 e = src[jj];
      val = make_float2(e.x, -e.y);        // conj(chirp)
    }
    buf[i] = val;
  }
  fft_dif_tab<512>(buf, tw);
  const float sc = 1.0f / 8192.0f;         // fold IFFT scaling into the filter
  for (int i = threadIdx.x; i < M_; i += 512)
    dst[i] = make_float2(buf[i].x * sc, buf[i].y * sc);
}

// ---------------- projection kernel v5: gll16 pipeline + LDS dot staging ----------------
// v4's wall diagnosis: scattered 4B global stores inside the stream loop share the vmcnt
// counter with loads, so every per-iter wait also waits for slow partial-line store
// retirement. v5 keeps results in LDS (lgkmcnt domain) and writes out ONCE, coalesced.
__device__ __forceinline__ void gll16(const float* gsrc, float* ldsbase) {
  __builtin_amdgcn_global_load_lds(
      (const __attribute__((address_space(1))) u32_t*)gsrc,
      (__attribute__((address_space(3))) u32_t*)ldsbase, 16, 0, 0);
}

extern "C" __global__ __launch_bounds__(256)
void proj_kernel(const float* __restrict__ queries, const float* __restrict__ keys,
                 const float* __restrict__ values,
                 const float* __restrict__ Wq, const float* __restrict__ bq,
                 const float* __restrict__ Wk, const float* __restrict__ bk,
                 const float* __restrict__ Wv, const float* __restrict__ bv,
                 float* __restrict__ q_ws, float* __restrict__ k_ws,
                 float* __restrict__ v_ws)
{
  __shared__ __align__(16) float lds[4][2][1024];   // 32 KB: wave x dbuf x tile
  __shared__ float dots_sh[3][8][64];               // 6 KB: staged results

  const int tid  = threadIdx.x;
  const int w    = tid >> 6;
  const int lane = tid & 63;
  const int q16  = lane & 15;          // d-quad within a 64-float head
  const int hi   = lane >> 4;          // head-subgroup 0..3
  const int blk  = blockIdx.x;         // 2048 blocks
  const int b    = blk >> 6;           // 0..31
  const int b8   = b * 8;
  const int lbase = (blk & 63) << 6;   // 64 rows per block

  const float* bases[3] = { queries + (size_t)b * 2097152,
                            keys    + (size_t)b * 2097152,
                            values  + (size_t)b * 2097152 };
  const float4 wv4[3] = { reinterpret_cast<const float4*>(Wq)[q16],
                          reinterpret_cast<const float4*>(Wk)[q16],
                          reinterpret_cast<const float4*>(Wv)[q16] };

  // iter IT = s*8 + i: input s, rows l0 = lbase + (i*4 + w)*2 (rows l0, l0+1)
#define PR_SRC(IT) (bases[(IT) >> 3] + (size_t)(lbase + ((((IT) & 7) << 2) + w) * 2) * 512)
#define PR_ISSUE(IT) { \
    const float* g_ = PR_SRC(IT); \
    float* l_ = lds[w][(IT) & 1]; \
    gll16(g_ + 0 * 256 + lane * 4, l_ + 0 * 256); \
    gll16(g_ + 1 * 256 + lane * 4, l_ + 1 * 256); \
    gll16(g_ + 2 * 256 + lane * 4, l_ + 2 * 256); \
    gll16(g_ + 3 * 256 + lane * 4, l_ + 3 * 256); }

  PR_ISSUE(0)
  #pragma unroll
  for (int it = 0; it < 24; ++it) {
    if (it + 1 < 24) { PR_ISSUE(it + 1) }
    // loop has NO global stores -> vmcnt counts only gll ops.
    // outstanding at wait: gll(it) [4] + gll(it+1) [4 if issued]; retire gll(it):
    if (it + 1 < 24) { asm volatile("s_waitcnt vmcnt(4)" ::: "memory"); }
    else             { asm volatile("s_waitcnt vmcnt(0)" ::: "memory"); }
    const int s_ = it >> 3;
    const float* L = lds[w][it & 1];
    const float4 wq_ = wv4[s_];
    float dj[4];
    #pragma unroll
    for (int j = 0; j < 4; ++j) {
      const float4 x = *reinterpret_cast<const float4*>(L + j * 256 + lane * 4);
      dj[j] = x.x * wq_.x + x.y * wq_.y + x.z * wq_.z + x.w * wq_.w;
    }
    #pragma unroll
    for (int j = 0; j < 4; ++j) {
      dj[j] += __shfl_xor(dj[j], 1);
      dj[j] += __shfl_xor(dj[j], 2);
      dj[j] += __shfl_xor(dj[j], 4);
      dj[j] += __shfl_xor(dj[j], 8);
    }
    if (q16 == 0) {
      const int lloc = (((it & 7) << 2) + w) * 2;
      #pragma unroll
      for (int j = 0; j < 4; ++j) {
        const int h = ((j & 1) << 2) + hi;
        dots_sh[s_][h][lloc + (j >> 1)] = dj[j];    // ds_write: lgkmcnt domain
      }
    }
  }
#undef PR_ISSUE
#undef PR_SRC

  __syncthreads();
  // single coalesced writeout: 24 runs x 64 floats (16 lanes x float4), 2 passes
  {
    const int l16 = tid & 15;
    const float bq0 = bq[0], bk0 = bk[0], bv0 = bv[0];
    #pragma unroll
    for (int pass = 0; pass < 2; ++pass) {
      const int rr = (tid >> 4) + pass * 16;
      if (rr < 24) {
        const int s_ = rr >> 3, h_ = rr & 7;
        const float bias = (s_ == 0 ? bq0 : (s_ == 1 ? bk0 : bv0));
        float* dst = (s_ == 0 ? q_ws : (s_ == 1 ? k_ws : v_ws));
        float4 o;
        o.x = dots_sh[s_][h_][l16 * 4 + 0] + bias;
        o.y = dots_sh[s_][h_][l16 * 4 + 1] + bias;
        o.z = dots_sh[s_][h_][l16 * 4 + 2] + bias;
        o.w = dots_sh[s_][h_][l16 * 4 + 3] + bias;
        *reinterpret_cast<float4*>(dst + ((size_t)(b8 + h_) << 12) + lbase + l16 * 4) = o;
      }
    }
  }
}

// ---------------- main kernel: radix-4 CZT with register-fused stage-0 passes (r13) ------
extern "C" __global__ __launch_bounds__(1024, 1)
void autocorr_main(const float2* __restrict__ ws,
                   const float* __restrict__ q_ws, const float* __restrict__ k_ws,
                   const float* __restrict__ v_ws, float* __restrict__ outp)
{
  __shared__ __align__(16) float2 bufA[M_];   // 64 KB (K path, then inverse-CZT)
  __shared__ __align__(16) float2 bufB[M_];   // 64 KB (Q path)
  __shared__ float  v_lds[L_];                // 16 KB
  __shared__ float  cand_v[16 * KK];
  __shared__ int    cand_i[16 * KK];
  __shared__ float  w_sh[KK];
  __shared__ int    i_sh[KK];

  const int tid = threadIdx.x;
  const int bh  = blockIdx.x;

  const float2* c_t = ws + WS_C;
  const float2* d_t = ws + WS_D;
  const float2* H1  = ws + WS_H1;
  const float2* H2  = ws + WS_H2;
  const float* qrow = q_ws + ((size_t)bh << 12);
  const float* krow = k_ws + ((size_t)bh << 12);
  const float* vrow = v_ws + ((size_t)bh << 12);

  // v into LDS (consumed only after many barriers)
  {
    const float4 v4 = reinterpret_cast<const float4*>(vrow)[tid];
    reinterpret_cast<float4*>(v_lds)[tid] = v4;
  }

  // ======== ENTRY FUSION: chirp-premultiply + conv2 forward s=0 (q=2048), registers ======
  #pragma unroll
  for (int r = 0; r < 2; ++r) {
    const int bid = tid + (r << 10);                 // j = i0 = bid (< 2048)
    const float2 w1 = twf(bid);
    const float2 w2 = cmulf(w1, w1);
    const float2 w3 = cmulf(w2, w1);
    const float2 cc0 = c_t[bid], cc1 = c_t[bid + 2048];
    const float k0 = krow[bid], k1 = krow[bid + 2048];
    const float q0 = qrow[bid], q1 = qrow[bid + 2048];
    float2 xa[4] = { make_float2(k0 * cc0.x, k0 * cc0.y),
                     make_float2(k1 * cc1.x, k1 * cc1.y),
                     make_float2(0.f, 0.f), make_float2(0.f, 0.f) };
    float2 xb[4] = { make_float2(q0 * cc0.x, q0 * cc0.y),
                     make_float2(q1 * cc1.x, q1 * cc1.y),
                     make_float2(0.f, 0.f), make_float2(0.f, 0.f) };
    bfly4_dif(xa, w1, w2, w3);
    bfly4_dif(xb, w1, w2, w3);
    #pragma unroll
    for (int k = 0; k < 4; ++k) {
      bufA[bid + k * 2048] = xa[k];
      bufB[bid + k * 2048] = xb[k];
    }
  }

  // conv2 middle: fwd s=1..5, midpair(H1), inv s=5..1
  fwd_stages2(bufA, bufB);
  __syncthreads();
  #pragma unroll
  for (int r = 0; r < 4; ++r) {
    const int p = tid + (r << 10);
    const float4 h = reinterpret_cast<const float4*>(H1)[p];
    reinterpret_cast<float4*>(bufA)[p] = midpair(reinterpret_cast<float4*>(bufA)[p], h);
    reinterpret_cast<float4*>(bufB)[p] = midpair(reinterpret_cast<float4*>(bufB)[p], h);
  }
  inv_stages2(bufA, bufB);
  __syncthreads();

  // ======== MIDDLE FUSION: conv2 inv s=0 + F-build + g.d + conv1 fwd s=0, registers =====
  {
    float2 gd[2][2];
    #pragma unroll
    for (int r = 0; r < 2; ++r) {
      const int bid = tid + (r << 10);
      const float2 w1 = twf(bid);
      const float2 w2 = cmulf(w1, w1);
      const float2 w3 = cmulf(w2, w1);
      float2 xa[4], xb[4];
      #pragma unroll
      for (int k = 0; k < 4; ++k) { xa[k] = bufA[bid + k * 2048]; xb[k] = bufB[bid + k * 2048]; }
      bfly4_dit(xa, w1, w2, w3);
      bfly4_dit(xb, w1, w2, w3);
      #pragma unroll
      for (int k = 0; k < 2; ++k) {                  // k>=2 are pad outputs: discarded
        const int m = bid + k * 2048;
        const float2 cc = c_t[m];
        const float2 K = cmulf(cc, xa[k]);
        const float2 Q = cmulf(cc, xb[k]);
        const float2 F = cmulcf(Q, K);
        float2 g;
        if (m == 0 || m == 4095) g = make_float2(F.x, 0.f);   // DC/Nyquist: Im dropped
        else                     g = make_float2(2.f * F.x, 2.f * F.y);
        gd[r][k] = cmulf(g, d_t[m]);
      }
    }
    #pragma unroll
    for (int r = 0; r < 2; ++r) {
      const int bid = tid + (r << 10);
      const float2 w1 = twf(bid);
      const float2 w2 = cmulf(w1, w1);
      const float2 w3 = cmulf(w2, w1);
      float2 x[4] = { gd[r][0], gd[r][1], make_float2(0.f, 0.f), make_float2(0.f, 0.f) };
      bfly4_dif(x, w1, w2, w3);
      #pragma unroll
      for (int k = 0; k < 4; ++k) bufA[bid + k * 2048] = x[k];
    }
  }

  // conv1 middle: fwd s=1..5, midpair(H2), inv s=5..1
  fwd_stages1(bufA);
  __syncthreads();
  #pragma unroll
  for (int r = 0; r < 4; ++r) {
    const int p = tid + (r << 10);
    const float4 h = reinterpret_cast<const float4*>(H2)[p];
    reinterpret_cast<float4*>(bufA)[p] = midpair(reinterpret_cast<float4*>(bufA)[p], h);
  }
  inv_stages1(bufA);
  __syncthreads();

  // ======== EXIT FUSION: conv1 inv s=0 + score, registers ========
  const float SCALE = (float)(1.0 / (8190.0 * 4096.0));   // /8190 (irfft) then /4096 (L)
  float svv[4]; int sii[4];
  #pragma unroll
  for (int r = 0; r < 2; ++r) {
    const int bid = tid + (r << 10);
    const float2 w1 = twf(bid);
    const float2 w2 = cmulf(w1, w1);
    const float2 w3 = cmulf(w2, w1);
    float2 x[4];
    #pragma unroll
    for (int k = 0; k < 4; ++k) x[k] = bufA[bid + k * 2048];
    bfly4_dit(x, w1, w2, w3);
    #pragma unroll
    for (int k = 0; k < 2; ++k) {                    // k>=2 are pad outputs: discarded
      const int t = bid + k * 2048;
      const float2 Z = cmulf(d_t[t], x[k]);
      svv[2 * r + k] = Z.x * SCALE;
      sii[2 * r + k] = t;
    }
  }

  // ---------------- per-wave top-45 ----------------
  const int lane = tid & 63, wv = tid >> 6;   // 16 waves
  for (int it = 0; it < KK; ++it) {
    float bvv = -FLT_MAX; int bii = 0x7fffffff;
    #pragma unroll
    for (int c = 0; c < 4; ++c)
      if (svv[c] > bvv || (svv[c] == bvv && sii[c] < bii)) { bvv = svv[c]; bii = sii[c]; }
    #pragma unroll
    for (int off = 1; off < 64; off <<= 1) {
      const float ov = __shfl_xor(bvv, off);
      const int   oi = __shfl_xor(bii, off);
      if (ov > bvv || (ov == bvv && oi < bii)) { bvv = ov; bii = oi; }
    }
    #pragma unroll
    for (int c = 0; c < 4; ++c) if (sii[c] == bii) svv[c] = -FLT_MAX;
    if (lane == 0) { cand_v[wv * KK + it] = bvv; cand_i[wv * KK + it] = bii; }
  }
  __syncthreads();

  // ---------------- merge 16x45 + softmax (wave 0) ----------------
  if (tid < 64) {
    float mv[12]; int mi[12];
    #pragma unroll
    for (int c = 0; c < 12; ++c) {
      const int id = tid + 64 * c;
      if (id < 16 * KK) { mv[c] = cand_v[id]; mi[c] = cand_i[id]; }
      else              { mv[c] = -FLT_MAX;   mi[c] = 0x7fffffff; }
    }
    float m0 = 0.f, sum = 0.f, myv = -FLT_MAX; int myi = 0;
    for (int it = 0; it < KK; ++it) {
      float bvv = -FLT_MAX; int bii = 0x7fffffff;
      #pragma unroll
      for (int c = 0; c < 12; ++c)
        if (mv[c] > bvv || (mv[c] == bvv && mi[c] < bii)) { bvv = mv[c]; bii = mi[c]; }
      #pragma unroll
      for (int off = 1; off < 64; off <<= 1) {
        const float ov = __shfl_xor(bvv, off);
        const int   oi = __shfl_xor(bii, off);
        if (ov > bvv || (ov == bvv && oi < bii)) { bvv = ov; bii = oi; }
      }
      if (it == 0) m0 = bvv;
      sum += expf(bvv - m0);               // identical on all lanes
      if (tid == it) { myv = bvv; myi = bii; }
      #pragma unroll
      for (int c = 0; c < 12; ++c) if (mi[c] == bii) mv[c] = -FLT_MAX;
    }
    if (tid < KK) { w_sh[tid] = expf(myv - m0) / sum; i_sh[tid] = myi; }
  }
  __syncthreads();

  // ---------------- gather: out[t] = sum_j w_j * v[(idx_j + t) & 4095] ------------
  {
    float acc[4] = {0, 0, 0, 0};
    for (int j = 0; j < KK; ++j) {
      const float wj = w_sh[j];
      const int   bse = i_sh[j] + tid;
      #pragma unroll
      for (int r = 0; r < 4; ++r)
        acc[r] = fmaf(wj, v_lds[(bse + (r << 10)) & (L_ - 1)], acc[r]);
    }
    float* op = outp + ((size_t)bh << 12);
    #pragma unroll
    for (int r = 0; r < 4; ++r) op[tid + (r << 10)] = acc[r];
  }
}

extern "C" void kernel_launch(void* const* d_in, const int* in_sizes, int n_in,
                              void* d_out, int out_size, void* d_ws, size_t ws_size,
                              hipStream_t stream) {
  const float* queries = (const float*)d_in[0];
  const float* keys    = (const float*)d_in[1];
  const float* values  = (const float*)d_in[2];
  const float* Wq = (const float*)d_in[3];
  const float* bq = (const float*)d_in[4];
  const float* Wk = (const float*)d_in[5];
  const float* bk = (const float*)d_in[6];
  const float* Wv = (const float*)d_in[7];
  const float* bv = (const float*)d_in[8];
  float2* ws = (float2*)d_ws;
  float* q_ws = (float*)d_ws + 2 * WS_QKV;
  float* k_ws = q_ws + (1 << 20);
  float* v_ws = k_ws + (1 << 20);
  float* out = (float*)d_out;

  hipLaunchKernelGGL(setup_tables,  dim3(32), dim3(512), 0, stream, ws);
  hipLaunchKernelGGL(setup_filters, dim3(2),  dim3(512), 0, stream, ws);
  hipLaunchKernelGGL(proj_kernel,   dim3(2048), dim3(256), 0, stream,
                     queries, keys, values, Wq, bq, Wk, bk, Wv, bv, q_ws, k_ws, v_ws);
  hipLaunchKernelGGL(autocorr_main, dim3(256), dim3(1024), 0, stream,
                     ws, q_ws, k_ws, v_ws, out);
}

// Round 18
// 314.809 us; speedup vs baseline: 1.1555x; 1.0187x over previous
//
#include <hip/hip_runtime.h>
#include <math.h>
#include <float.h>

#define L_   4096
#define M_   8192
#define H_   8
#define D_   64
#define KK   45          // 5 * ceil(ln(4096))

// ws layout in float2 units
#define WS_C   0         // c[4096]  : e^{-i pi j^2 / 8191}
#define WS_D   4096      // d[4096]  : e^{+i pi j^2 / 8190}
#define WS_TW  8192      // tw[8192] : e^{-2 pi i j / 8192} (fp64-accurate; setup_filters only)
#define WS_H1  16384     // H1s[8192]: radix4-DIF(conj-chirp c), pre-scaled 1/8192, digit-reversed
#define WS_H2  24576     // H2s[8192]: same for d
#define WS_QKV 32768     // float2 offset where staged q/k/v planes start
// tables: 256 KB; then q/k/v planes: 3 x 1M floats = 12 MB

typedef unsigned int u32_t;

__device__ __forceinline__ float2 cadd(float2 a, float2 b) { return make_float2(a.x + b.x, a.y + b.y); }
__device__ __forceinline__ float2 csub(float2 a, float2 b) { return make_float2(a.x - b.x, a.y - b.y); }
__device__ __forceinline__ float2 cmulf(float2 a, float2 b) {
  return make_float2(a.x * b.x - a.y * b.y, a.x * b.y + a.y * b.x);
}
__device__ __forceinline__ float2 cmulcf(float2 a, float2 b) {  // a * conj(b)
  return make_float2(a.x * b.x + a.y * b.y, a.y * b.x - a.x * b.y);
}

// register twiddle: e^{-2 pi i e / 8192}, e in [0, 2048)
__device__ __forceinline__ float2 twf(int e) {
  float s, c;
  __sincosf((float)e * -7.66990394e-4f, &s, &c);   // -2*pi/8192
  return make_float2(c, s);
}

#define R4DIF(BUF) { \
  const float2 a = BUF[i0], b = BUF[i0 + q], c = BUF[i0 + 2 * q], d = BUF[i0 + 3 * q]; \
  const float2 t0 = cadd(a, c), t1 = csub(a, c), t2 = cadd(b, d), t3 = csub(b, d); \
  BUF[i0]         = cadd(t0, t2); \
  BUF[i0 + q]     = cmulf(make_float2(t1.x + t3.y, t1.y - t3.x), w1); \
  BUF[i0 + 2 * q] = cmulf(csub(t0, t2), w2); \
  BUF[i0 + 3 * q] = cmulf(make_float2(t1.x - t3.y, t1.y + t3.x), w3); }

#define R4DIT(BUF) { \
  const float2 z0 = BUF[i0]; \
  const float2 z1 = cmulcf(BUF[i0 + q],     w1); \
  const float2 z2 = cmulcf(BUF[i0 + 2 * q], w2); \
  const float2 z3 = cmulcf(BUF[i0 + 3 * q], w3); \
  const float2 t0 = cadd(z0, z2), t1 = csub(z0, z2), t2 = cadd(z1, z3), u = csub(z1, z3); \
  BUF[i0]         = cadd(t0, t2); \
  BUF[i0 + q]     = make_float2(t1.x - u.y, t1.y + u.x); \
  BUF[i0 + 2 * q] = csub(t0, t2); \
  BUF[i0 + 3 * q] = make_float2(t1.x + u.y, t1.y - u.x); }

// register-array radix-4 butterflies (all indices compile-time at call sites)
__device__ __forceinline__ void bfly4_dif(float2 x[4], float2 w1, float2 w2, float2 w3) {
  const float2 t0 = cadd(x[0], x[2]), t1 = csub(x[0], x[2]);
  const float2 t2 = cadd(x[1], x[3]), t3 = csub(x[1], x[3]);
  x[0] = cadd(t0, t2);
  x[1] = cmulf(make_float2(t1.x + t3.y, t1.y - t3.x), w1);
  x[2] = cmulf(csub(t0, t2), w2);
  x[3] = cmulf(make_float2(t1.x - t3.y, t1.y + t3.x), w3);
}
__device__ __forceinline__ void bfly4_dit(float2 x[4], float2 w1, float2 w2, float2 w3) {
  const float2 z0 = x[0];
  const float2 z1 = cmulcf(x[1], w1);
  const float2 z2 = cmulcf(x[2], w2);
  const float2 z3 = cmulcf(x[3], w3);
  const float2 t0 = cadd(z0, z2), t1 = csub(z0, z2), t2 = cadd(z1, z3), u = csub(z1, z3);
  x[0] = cadd(t0, t2);
  x[1] = make_float2(t1.x - u.y, t1.y + u.x);
  x[2] = csub(t0, t2);
  x[3] = make_float2(t1.x + u.y, t1.y - u.x);
}

// fused r2 + H-pointwise + r2inv on one float2-pair packed in a float4
__device__ __forceinline__ float4 midpair(float4 a, float4 h) {
  float2 u = make_float2(a.x + a.z, a.y + a.w);
  float2 v = make_float2(a.x - a.z, a.y - a.w);
  u = cmulf(u, make_float2(h.x, h.y));
  v = cmulf(v, make_float2(h.z, h.w));
  return make_float4(u.x + v.x, u.y + v.y, u.x - v.x, u.y - v.y);
}

// middle forward stages s=1..5 on two buffers (1024 threads)
static __device__ void fwd_stages2(float2* A, float2* B) {
  const int tid = threadIdx.x;
  #pragma unroll
  for (int s = 1; s < 6; ++s) {
    const int q = 2048 >> (2 * s);
    __syncthreads();
    #pragma unroll
    for (int r = 0; r < 2; ++r) {
      const int bid = tid + (r << 10);
      const int j   = bid & (q - 1);
      const int i0  = ((bid >> (11 - 2 * s)) << (13 - 2 * s)) + j;
      const float2 w1 = twf(j << (2 * s));
      const float2 w2 = cmulf(w1, w1);
      const float2 w3 = cmulf(w2, w1);
      R4DIF(A) R4DIF(B)
    }
  }
}
static __device__ void inv_stages2(float2* A, float2* B) {   // s=5..1
  const int tid = threadIdx.x;
  #pragma unroll
  for (int s = 5; s >= 1; --s) {
    const int q = 2048 >> (2 * s);
    __syncthreads();
    #pragma unroll
    for (int r = 0; r < 2; ++r) {
      const int bid = tid + (r << 10);
      const int j   = bid & (q - 1);
      const int i0  = ((bid >> (11 - 2 * s)) << (13 - 2 * s)) + j;
      const float2 w1 = twf(j << (2 * s));
      const float2 w2 = cmulf(w1, w1);
      const float2 w3 = cmulf(w2, w1);
      R4DIT(A) R4DIT(B)
    }
  }
}
static __device__ void fwd_stages1(float2* A) {
  const int tid = threadIdx.x;
  #pragma unroll
  for (int s = 1; s < 6; ++s) {
    const int q = 2048 >> (2 * s);
    __syncthreads();
    #pragma unroll
    for (int r = 0; r < 2; ++r) {
      const int bid = tid + (r << 10);
      const int j   = bid & (q - 1);
      const int i0  = ((bid >> (11 - 2 * s)) << (13 - 2 * s)) + j;
      const float2 w1 = twf(j << (2 * s));
      const float2 w2 = cmulf(w1, w1);
      const float2 w3 = cmulf(w2, w1);
      R4DIF(A)
    }
  }
}
static __device__ void inv_stages1(float2* A) {
  const int tid = threadIdx.x;
  #pragma unroll
  for (int s = 5; s >= 1; --s) {
    const int q = 2048 >> (2 * s);
    __syncthreads();
    #pragma unroll
    for (int r = 0; r < 2; ++r) {
      const int bid = tid + (r << 10);
      const int j   = bid & (q - 1);
      const int i0  = ((bid >> (11 - 2 * s)) << (13 - 2 * s)) + j;
      const float2 w1 = twf(j << (2 * s));
      const float2 w2 = cmulf(w1, w1);
      const float2 w3 = cmulf(w2, w1);
      R4DIT(A)
    }
  }
}

// ---------------- setup: tables (fp64) + Bluestein filters ----------------
template <int NT>
static __device__ void fft_dif_tab(float2* buf, const float2* __restrict__ tw) {
  const int tid = threadIdx.x;
  for (int s = 0; s < 6; ++s) {
    const int q = 2048 >> (2 * s);
    __syncthreads();
    for (int r = 0; r < 2048 / NT; ++r) {
      const int bid = tid + r * NT;
      const int j   = bid & (q - 1);
      const int i0  = ((bid >> (11 - 2 * s)) << (13 - 2 * s)) + j;
      const int e   = j << (2 * s);
      const float2 w1 = tw[e], w2 = tw[2 * e], w3 = tw[3 * e];
      R4DIF(buf)
    }
  }
  __syncthreads();
  for (int r = 0; r < 4096 / NT; ++r) {
    const int i0 = (tid + r * NT) << 1;
    const float2 a = buf[i0], b = buf[i0 + 1];
    buf[i0] = cadd(a, b); buf[i0 + 1] = csub(a, b);
  }
  __syncthreads();
}

extern "C" __global__ void setup_tables(float2* ws) {
  const int idx = blockIdx.x * 512 + threadIdx.x;
  if (idx < 4096) {
    const long p = ((long)idx * idx) % 16382;      // j^2 mod 2*8191
    const double th = -M_PI * (double)p / 8191.0;
    double s, c; sincos(th, &s, &c);
    ws[WS_C + idx] = make_float2((float)c, (float)s);
  } else if (idx < 8192) {
    const int j = idx - 4096;
    const long p = ((long)j * j) % 16380;          // j^2 mod 2*8190
    const double th = M_PI * (double)p / 8190.0;
    double s, c; sincos(th, &s, &c);
    ws[WS_D + j] = make_float2((float)c, (float)s);
  } else if (idx < 16384) {
    const int j = idx - 8192;
    const double th = -M_PI * (double)j / 4096.0;  // e^{-2pi i j/8192}
    double s, c; sincos(th, &s, &c);
    ws[WS_TW + j] = make_float2((float)c, (float)s);
  }
}

extern "C" __global__ __launch_bounds__(512, 1) void setup_filters(float2* ws) {
  __shared__ __align__(16) float2 buf[M_];
  const float2* src = ws + (blockIdx.x == 0 ? WS_C : WS_D);
  float2*       dst = ws + (blockIdx.x == 0 ? WS_H1 : WS_H2);
  const float2* tw  = ws + WS_TW;
  for (int i = threadIdx.x; i < M_; i += 512) {
    float2 val = make_float2(0.f, 0.f);
    if (i != 4096) {                       // kernel support |j| <= 4095
      const int jj = (i <= 4095) ? i : (M_ - i);   // chirp is even in j
      const float2 e = src[jj];
      val = make_float2(e.x, -e.y);        // conj(chirp)
    }
    buf[i] = val;
  }
  fft_dif_tab<512>(buf, tw);
  const float sc = 1.0f / 8192.0f;         // fold IFFT scaling into the filter
  for (int i = threadIdx.x; i < M_; i += 512)
    dst[i] = make_float2(buf[i].x * sc, buf[i].y * sc);
}

// ---------------- projection kernel v6: ONE contiguous 512KB stream per block ------------
// Grid 1536 = 3 inputs x 32 b x 16 row-chunks. Block reads rows [r0, r0+256) of ONE input
// (contiguous 512 KB), so each block drives a single DRAM stream (vs 3 interleaved in
// v1-v5 -- the suspected ~3.8 TB/s limiter). Depth-3 gll16 pipeline, 12 KB in flight per
// wave; vmcnt counts only gll ops; dots staged in LDS; one coalesced writeout.
__device__ __forceinline__ void gll16(const float* gsrc, float* ldsbase) {
  __builtin_amdgcn_global_load_lds(
      (const __attribute__((address_space(1))) u32_t*)gsrc,
      (__attribute__((address_space(3))) u32_t*)ldsbase, 16, 0, 0);
}

extern "C" __global__ __launch_bounds__(256)
void proj_kernel(const float* __restrict__ queries, const float* __restrict__ keys,
                 const float* __restrict__ values,
                 const float* __restrict__ Wq, const float* __restrict__ bq,
                 const float* __restrict__ Wk, const float* __restrict__ bk,
                 const float* __restrict__ Wv, const float* __restrict__ bv,
                 float* __restrict__ q_ws, float* __restrict__ k_ws,
                 float* __restrict__ v_ws)
{
  __shared__ __align__(16) float lds[4][3][1024];   // 48 KB: wave x depth3 x 2-row tile
  __shared__ float dots_sh[8][256];                 // 8 KB: head x row

  const int tid  = threadIdx.x;
  const int w    = tid >> 6;
  const int lane = tid & 63;
  const int q16  = lane & 15;          // d-quad within a 64-float head
  const int hi   = lane >> 4;          // head-subgroup 0..3
  const int blk  = blockIdx.x;         // 1536 blocks
  const int s    = blk >> 9;           // 0=q 1=k 2=v
  const int rem  = blk & 511;
  const int b    = rem >> 4;           // 0..31
  const int rc   = rem & 15;           // row chunk
  const int r0   = rc << 8;            // 256 rows per block
  const int b8   = b * 8;

  const float* base = (s == 0 ? queries : (s == 1 ? keys : values))
                      + (size_t)b * 2097152 + (size_t)r0 * 512;
  const float4* W4p = reinterpret_cast<const float4*>(s == 0 ? Wq : (s == 1 ? Wk : Wv));
  const float4 wq_ = W4p[q16];
  const float bias = (s == 0 ? bq[0] : (s == 1 ? bk[0] : bv[0]));

  // wave w handles tiles T = it*4 + w, it = 0..31; tile T = rows {2T, 2T+1} (local)
#define PR_SRC(IT) (base + (size_t)((((IT) << 2) + w) << 1) * 512)
#define PR_ISSUE(IT) { \
    const float* g_ = PR_SRC(IT); \
    float* l_ = lds[w][(IT) % 3]; \
    gll16(g_ + 0 * 256 + lane * 4, l_ + 0 * 256); \
    gll16(g_ + 1 * 256 + lane * 4, l_ + 1 * 256); \
    gll16(g_ + 2 * 256 + lane * 4, l_ + 2 * 256); \
    gll16(g_ + 3 * 256 + lane * 4, l_ + 3 * 256); }

  PR_ISSUE(0)
  PR_ISSUE(1)
  PR_ISSUE(2)
  #pragma unroll
  for (int it = 0; it < 32; ++it) {
    // outstanding tiles: {it .. min(it+2,31)}; retire tile it:
    if (it <= 29)      { asm volatile("s_waitcnt vmcnt(8)" ::: "memory"); }
    else if (it == 30) { asm volatile("s_waitcnt vmcnt(4)" ::: "memory"); }
    else               { asm volatile("s_waitcnt vmcnt(0)" ::: "memory"); }
    const float* L = lds[w][it % 3];
    float dj[4];
    #pragma unroll
    for (int j = 0; j < 4; ++j) {
      const float4 x = *reinterpret_cast<const float4*>(L + j * 256 + lane * 4);
      dj[j] = x.x * wq_.x + x.y * wq_.y + x.z * wq_.z + x.w * wq_.w;
    }
    #pragma unroll
    for (int j = 0; j < 4; ++j) {
      dj[j] += __shfl_xor(dj[j], 1);
      dj[j] += __shfl_xor(dj[j], 2);
      dj[j] += __shfl_xor(dj[j], 4);
      dj[j] += __shfl_xor(dj[j], 8);
    }
    if (q16 == 0) {
      const int rl = (((it << 2) + w) << 1);       // local row of tile
      #pragma unroll
      for (int j = 0; j < 4; ++j) {
        const int h = ((j & 1) << 2) + hi;
        dots_sh[h][rl + (j >> 1)] = dj[j];         // ds_write: lgkmcnt domain
      }
    }
    if (it + 3 < 32) { PR_ISSUE(it + 3) }          // reuse buffer just consumed
  }
#undef PR_ISSUE
#undef PR_SRC

  __syncthreads();
  // coalesced writeout: 8 heads x 256 floats (= 512 float4, 2 per thread)
  {
    float* dst = (s == 0 ? q_ws : (s == 1 ? k_ws : v_ws));
    #pragma unroll
    for (int p = 0; p < 2; ++p) {
      const int fl4 = tid + (p << 8);              // 0..511
      const int h   = fl4 >> 6;
      const int i64 = fl4 & 63;
      float4 o;
      o.x = dots_sh[h][i64 * 4 + 0] + bias;
      o.y = dots_sh[h][i64 * 4 + 1] + bias;
      o.z = dots_sh[h][i64 * 4 + 2] + bias;
      o.w = dots_sh[h][i64 * 4 + 3] + bias;
      reinterpret_cast<float4*>(dst + ((size_t)(b8 + h) << 12) + r0)[i64] = o;
    }
  }
}

// ---------------- main kernel: radix-4 CZT with register-fused stage-0 passes (r13) ------
extern "C" __global__ __launch_bounds__(1024, 1)
void autocorr_main(const float2* __restrict__ ws,
                   const float* __restrict__ q_ws, const float* __restrict__ k_ws,
                   const float* __restrict__ v_ws, float* __restrict__ outp)
{
  __shared__ __align__(16) float2 bufA[M_];   // 64 KB (K path, then inverse-CZT)
  __shared__ __align__(16) float2 bufB[M_];   // 64 KB (Q path)
  __shared__ float  v_lds[L_];                // 16 KB
  __shared__ float  cand_v[16 * KK];
  __shared__ int    cand_i[16 * KK];
  __shared__ float  w_sh[KK];
  __shared__ int    i_sh[KK];

  const int tid = threadIdx.x;
  const int bh  = blockIdx.x;

  const float2* c_t = ws + WS_C;
  const float2* d_t = ws + WS_D;
  const float2* H1  = ws + WS_H1;
  const float2* H2  = ws + WS_H2;
  const float* qrow = q_ws + ((size_t)bh << 12);
  const float* krow = k_ws + ((size_t)bh << 12);
  const float* vrow = v_ws + ((size_t)bh << 12);

  // v into LDS (consumed only after many barriers)
  {
    const float4 v4 = reinterpret_cast<const float4*>(vrow)[tid];
    reinterpret_cast<float4*>(v_lds)[tid] = v4;
  }

  // ======== ENTRY FUSION: chirp-premultiply + conv2 forward s=0 (q=2048), registers ======
  #pragma unroll
  for (int r = 0; r < 2; ++r) {
    const int bid = tid + (r << 10);                 // j = i0 = bid (< 2048)
    const float2 w1 = twf(bid);
    const float2 w2 = cmulf(w1, w1);
    const float2 w3 = cmulf(w2, w1);
    const float2 cc0 = c_t[bid], cc1 = c_t[bid + 2048];
    const float k0 = krow[bid], k1 = krow[bid + 2048];
    const float q0 = qrow[bid], q1 = qrow[bid + 2048];
    float2 xa[4] = { make_float2(k0 * cc0.x, k0 * cc0.y),
                     make_float2(k1 * cc1.x, k1 * cc1.y),
                     make_float2(0.f, 0.f), make_float2(0.f, 0.f) };
    float2 xb[4] = { make_float2(q0 * cc0.x, q0 * cc0.y),
                     make_float2(q1 * cc1.x, q1 * cc1.y),
                     make_float2(0.f, 0.f), make_float2(0.f, 0.f) };
    bfly4_dif(xa, w1, w2, w3);
    bfly4_dif(xb, w1, w2, w3);
    #pragma unroll
    for (int k = 0; k < 4; ++k) {
      bufA[bid + k * 2048] = xa[k];
      bufB[bid + k * 2048] = xb[k];
    }
  }

  // conv2 middle: fwd s=1..5, midpair(H1), inv s=5..1
  fwd_stages2(bufA, bufB);
  __syncthreads();
  #pragma unroll
  for (int r = 0; r < 4; ++r) {
    const int p = tid + (r << 10);
    const float4 h = reinterpret_cast<const float4*>(H1)[p];
    reinterpret_cast<float4*>(bufA)[p] = midpair(reinterpret_cast<float4*>(bufA)[p], h);
    reinterpret_cast<float4*>(bufB)[p] = midpair(reinterpret_cast<float4*>(bufB)[p], h);
  }
  inv_stages2(bufA, bufB);
  __syncthreads();

  // ======== MIDDLE FUSION: conv2 inv s=0 + F-build + g.d + conv1 fwd s=0, registers =====
  {
    float2 gd[2][2];
    #pragma unroll
    for (int r = 0; r < 2; ++r) {
      const int bid = tid + (r << 10);
      const float2 w1 = twf(bid);
      const float2 w2 = cmulf(w1, w1);
      const float2 w3 = cmulf(w2, w1);
      float2 xa[4], xb[4];
      #pragma unroll
      for (int k = 0; k < 4; ++k) { xa[k] = bufA[bid + k * 2048]; xb[k] = bufB[bid + k * 2048]; }
      bfly4_dit(xa, w1, w2, w3);
      bfly4_dit(xb, w1, w2, w3);
      #pragma unroll
      for (int k = 0; k < 2; ++k) {                  // k>=2 are pad outputs: discarded
        const int m = bid + k * 2048;
        const float2 cc = c_t[m];
        const float2 K = cmulf(cc, xa[k]);
        const float2 Q = cmulf(cc, xb[k]);
        const float2 F = cmulcf(Q, K);
        float2 g;
        if (m == 0 || m == 4095) g = make_float2(F.x, 0.f);   // DC/Nyquist: Im dropped
        else                     g = make_float2(2.f * F.x, 2.f * F.y);
        gd[r][k] = cmulf(g, d_t[m]);
      }
    }
    #pragma unroll
    for (int r = 0; r < 2; ++r) {
      const int bid = tid + (r << 10);
      const float2 w1 = twf(bid);
      const float2 w2 = cmulf(w1, w1);
      const float2 w3 = cmulf(w2, w1);
      float2 x[4] = { gd[r][0], gd[r][1], make_float2(0.f, 0.f), make_float2(0.f, 0.f) };
      bfly4_dif(x, w1, w2, w3);
      #pragma unroll
      for (int k = 0; k < 4; ++k) bufA[bid + k * 2048] = x[k];
    }
  }

  // conv1 middle: fwd s=1..5, midpair(H2), inv s=5..1
  fwd_stages1(bufA);
  __syncthreads();
  #pragma unroll
  for (int r = 0; r < 4; ++r) {
    const int p = tid + (r << 10);
    const float4 h = reinterpret_cast<const float4*>(H2)[p];
    reinterpret_cast<float4*>(bufA)[p] = midpair(reinterpret_cast<float4*>(bufA)[p], h);
  }
  inv_stages1(bufA);
  __syncthreads();

  // ======== EXIT FUSION: conv1 inv s=0 + score, registers ========
  const float SCALE = (float)(1.0 / (8190.0 * 4096.0));   // /8190 (irfft) then /4096 (L)
  float svv[4]; int sii[4];
  #pragma unroll
  for (int r = 0; r < 2; ++r) {
    const int bid = tid + (r << 10);
    const float2 w1 = twf(bid);
    const float2 w2 = cmulf(w1, w1);
    const float2 w3 = cmulf(w2, w1);
    float2 x[4];
    #pragma unroll
    for (int k = 0; k < 4; ++k) x[k] = bufA[bid + k * 2048];
    bfly4_dit(x, w1, w2, w3);
    #pragma unroll
    for (int k = 0; k < 2; ++k) {                    // k>=2 are pad outputs: discarded
      const int t = bid + k * 2048;
      const float2 Z = cmulf(d_t[t], x[k]);
      svv[2 * r + k] = Z.x * SCALE;
      sii[2 * r + k] = t;
    }
  }

  // ---------------- per-wave top-45 ----------------
  const int lane = tid & 63, wv = tid >> 6;   // 16 waves
  for (int it = 0; it < KK; ++it) {
    float bvv = -FLT_MAX; int bii = 0x7fffffff;
    #pragma unroll
    for (int c = 0; c < 4; ++c)
      if (svv[c] > bvv || (svv[c] == bvv && sii[c] < bii)) { bvv = svv[c]; bii = sii[c]; }
    #pragma unroll
    for (int off = 1; off < 64; off <<= 1) {
      const float ov = __shfl_xor(bvv, off);
      const int   oi = __shfl_xor(bii, off);
      if (ov > bvv || (ov == bvv && oi < bii)) { bvv = ov; bii = oi; }
    }
    #pragma unroll
    for (int c = 0; c < 4; ++c) if (sii[c] == bii) svv[c] = -FLT_MAX;
    if (lane == 0) { cand_v[wv * KK + it] = bvv; cand_i[wv * KK + it] = bii; }
  }
  __syncthreads();

  // ---------------- merge 16x45 + softmax (wave 0) ----------------
  if (tid < 64) {
    float mv[12]; int mi[12];
    #pragma unroll
    for (int c = 0; c < 12; ++c) {
      const int id = tid + 64 * c;
      if (id < 16 * KK) { mv[c] = cand_v[id]; mi[c] = cand_i[id]; }
      else              { mv[c] = -FLT_MAX;   mi[c] = 0x7fffffff; }
    }
    float m0 = 0.f, sum = 0.f, myv = -FLT_MAX; int myi = 0;
    for (int it = 0; it < KK; ++it) {
      float bvv = -FLT_MAX; int bii = 0x7fffffff;
      #pragma unroll
      for (int c = 0; c < 12; ++c)
        if (mv[c] > bvv || (mv[c] == bvv && mi[c] < bii)) { bvv = mv[c]; bii = mi[c]; }
      #pragma unroll
      for (int off = 1; off < 64; off <<= 1) {
        const float ov = __shfl_xor(bvv, off);
        const int   oi = __shfl_xor(bii, off);
        if (ov > bvv || (ov == bvv && oi < bii)) { bvv = ov; bii = oi; }
      }
      if (it == 0) m0 = bvv;
      sum += expf(bvv - m0);               // identical on all lanes
      if (tid == it) { myv = bvv; myi = bii; }
      #pragma unroll
      for (int c = 0; c < 12; ++c) if (mi[c] == bii) mv[c] = -FLT_MAX;
    }
    if (tid < KK) { w_sh[tid] = expf(myv - m0) / sum; i_sh[tid] = myi; }
  }
  __syncthreads();

  // ---------------- gather: out[t] = sum_j w_j * v[(idx_j + t) & 4095] ------------
  {
    float acc[4] = {0, 0, 0, 0};
    for (int j = 0; j < KK; ++j) {
      const float wj = w_sh[j];
      const int   bse = i_sh[j] + tid;
      #pragma unroll
      for (int r = 0; r < 4; ++r)
        acc[r] = fmaf(wj, v_lds[(bse + (r << 10)) & (L_ - 1)], acc[r]);
    }
    float* op = outp + ((size_t)bh << 12);
    #pragma unroll
    for (int r = 0; r < 4; ++r) op[tid + (r << 10)] = acc[r];
  }
}

extern "C" void kernel_launch(void* const* d_in, const int* in_sizes, int n_in,
                              void* d_out, int out_size, void* d_ws, size_t ws_size,
                              hipStream_t stream) {
  const float* queries = (const float*)d_in[0];
  const float* keys    = (const float*)d_in[1];
  const float* values  = (const float*)d_in[2];
  const float* Wq = (const float*)d_in[3];
  const float* bq = (const float*)d_in[4];
  const float* Wk = (const float*)d_in[5];
  const float* bk = (const float*)d_in[6];
  const float* Wv = (const float*)d_in[7];
  const float* bv = (const float*)d_in[8];
  float2* ws = (float2*)d_ws;
  float* q_ws = (float*)d_ws + 2 * WS_QKV;
  float* k_ws = q_ws + (1 << 20);
  float* v_ws = k_ws + (1 << 20);
  float* out = (float*)d_out;

  hipLaunchKernelGGL(setup_tables,  dim3(32), dim3(512), 0, stream, ws);
  hipLaunchKernelGGL(setup_filters, dim3(2),  dim3(512), 0, stream, ws);
  hipLaunchKernelGGL(proj_kernel,   dim3(1536), dim3(256), 0, stream,
                     queries, keys, values, Wq, bq, Wk, bk, Wv, bv, q_ws, k_ws, v_ws);
  hipLaunchKernelGGL(autocorr_main, dim3(256), dim3(1024), 0, stream,
                     ws, q_ws, k_ws, v_ws, out);
}